// Round 13
// baseline (387.088 us; speedup 1.0000x reference)
//
#include <hip/hip_runtime.h>

// Problem constants (from reference)
#define NVN 65536
#define NCN 32768
#define NB 4
#define DIM 32
#define NE 262144
#define HID 40
#define MSGD 20
#define SLOT 40        // edge slots per check node (Poisson(8) max-deg ~25 << 40)
#define WE2_STRIDE 36  // padded row stride for we2s (breaks h-row bank aliasing)

typedef unsigned short u16;
typedef unsigned int u32;

// bf16 helpers (RNE pack, cheap unpack)
__device__ __forceinline__ u16 f2bf(float f) {
    u32 u = __float_as_uint(f);
    u += 0x7fff + ((u >> 16) & 1);
    return (u16)(u >> 16);
}
__device__ __forceinline__ float bflo(u32 u) { return __uint_as_float(u << 16); }
__device__ __forceinline__ float bfhi(u32 u) { return __uint_as_float(u & 0xffff0000u); }

__device__ __forceinline__ void fma4(float4& acc, float a, const float4 w) {
    acc.x += a * w.x; acc.y += a * w.y; acc.z += a * w.z; acc.w += a * w.w;
}

// ---------------- direct slot-scatter (replaces hist+scan+scatter) ----------------

__global__ __launch_bounds__(256) void scatter_slot(const int* __restrict__ to_x,
                                                    const int* __restrict__ from_x,
                                                    const int* __restrict__ to_z,
                                                    const int* __restrict__ from_z,
                                                    int* __restrict__ cnt_x,
                                                    int* __restrict__ cnt_z,
                                                    u16* __restrict__ ef_x,
                                                    u16* __restrict__ ef_z) {
    int bid = blockIdx.x;
    int e = (bid & 1023) * 256 + threadIdx.x;
    const int* t; const int* f; int* cnt; u16* ef;
    if (bid < 1024) { t = to_x; f = from_x; cnt = cnt_x; ef = ef_x; }
    else            { t = to_z; f = from_z; cnt = cnt_z; ef = ef_z; }
    int c = t[e];
    int pos = atomicAdd(&cnt[c], 1);
    if (pos < SLOT) ef[c * SLOT + pos] = (u16)f[e];
}

// ------- Precompute U2h, BOTH sides, 20 outputs/thread, LANE-INTERLEAVED layout -------
// Per v: 320B line; lane l8's 20 bf16 live at {v*320 + l8*16, +128+l8*16, +256+l8*8}.

__global__ __launch_bounds__(256) void precompU_both(const float* __restrict__ h_from,
                                                     const float* __restrict__ Wm1_x,
                                                     const float* __restrict__ Wm1_z,
                                                     u16* __restrict__ U2h_x,
                                                     u16* __restrict__ U2h_z) {
    int side = blockIdx.x >> 11;
    const float* Wm1 = side ? Wm1_z : Wm1_x;
    u16* U2h = side ? U2h_z : U2h_x;

    __shared__ __attribute__((aligned(16))) float w[DIM * HID];
    int tid = threadIdx.x;
    for (int i = tid; i < DIM * HID; i += 256) w[i] = Wm1[i];
    __syncthreads();

    int gt = (blockIdx.x & 2047) * 256 + tid;
    int v = gt >> 3;
    int l8 = gt & 7;
    int b = l8 & 3;
    int hoff = (l8 >> 2) * 20;

    const float4* hf4 = (const float4*)(h_from + ((size_t)b * NVN + v) * DIM);
    float4 acc4[5];
#pragma unroll
    for (int jq = 0; jq < 5; jq++) acc4[jq] = make_float4(0.f, 0.f, 0.f, 0.f);
#pragma unroll
    for (int q = 0; q < DIM / 4; q++) {
        float4 x = hf4[q];
#define WROW(xr, row) { const float4* w4_ = (const float4*)(w + (row) * HID + hoff); \
        fma4(acc4[0], (xr), w4_[0]); fma4(acc4[1], (xr), w4_[1]); \
        fma4(acc4[2], (xr), w4_[2]); fma4(acc4[3], (xr), w4_[3]); \
        fma4(acc4[4], (xr), w4_[4]); }
        WROW(x.x, 4 * q + 0) WROW(x.y, 4 * q + 1) WROW(x.z, 4 * q + 2) WROW(x.w, 4 * q + 3)
#undef WROW
    }
    u32 p[10];
#pragma unroll
    for (int jq = 0; jq < 5; jq++) {
        p[2 * jq]     = (u32)f2bf(acc4[jq].x) | ((u32)f2bf(acc4[jq].y) << 16);
        p[2 * jq + 1] = (u32)f2bf(acc4[jq].z) | ((u32)f2bf(acc4[jq].w) << 16);
    }
    char* dst = (char*)U2h + (size_t)v * 320;
    *(uint4*)(dst + l8 * 16)       = make_uint4(p[0], p[1], p[2], p[3]);
    *(uint4*)(dst + 128 + l8 * 16) = make_uint4(p[4], p[5], p[6], p[7]);
    *(uint2*)(dst + 256 + l8 * 8)  = make_uint2(p[8], p[9]);
}

// ------- aggA: inline t-matvec + gather + relu-sum -> s (bf16), BOTH sides -------
// Engineered for VGPR <= 64 (the 8-waves/SIMD cliff): t kept PACKED as 10 u32,
// s[20] f32, two 3-load banks (20 regs). No matvec phases here (moved to aggB).
// NOTE: no min-waves clamp — if VGPR floats past 64 the bet is lost but no spill.

__global__ __launch_bounds__(256) void aggA_kernel(
        const u16* __restrict__ U2h_x, const u16* __restrict__ U2h_z,
        const float* __restrict__ h_to_x, const float* __restrict__ h_to_z,
        const int* __restrict__ cnt_x, const int* __restrict__ cnt_z,
        const u16* __restrict__ ef_x, const u16* __restrict__ ef_z,
        const float* __restrict__ Wm1_x, const float* __restrict__ Wm1_z,
        u16* __restrict__ s_buf) {
    int side = blockIdx.x >> 10;
    const u16* U2h = side ? U2h_z : U2h_x;
    const float* h_to = side ? h_to_z : h_to_x;
    const int* cnt = side ? cnt_z : cnt_x;
    const u16* ef = side ? ef_z : ef_x;
    const float* Wm1 = side ? Wm1_z : Wm1_x;

    __shared__ __attribute__((aligned(16))) float wm1b[DIM * HID];  // Wm1 rows 32..63
    int tid = threadIdx.x;
    for (int i = tid; i < DIM * HID; i += 256) wm1b[i] = Wm1[DIM * HID + i];
    __syncthreads();

    int gt = (blockIdx.x & 1023) * 256 + tid;
    int c = gt >> 3;
    int l8 = gt & 7;
    int b = l8 & 3;
    int hoff = (l8 >> 2) * 20;

    // ---- t = h_to[b][c] @ Wm1[32:64][:, hoff:hoff+20], packed to bf16 pairs ----
    u32 tp[10];
    {
        float4 t4[5];
#pragma unroll
        for (int jq = 0; jq < 5; jq++) t4[jq] = make_float4(0.f, 0.f, 0.f, 0.f);
        const float4* Xp = (const float4*)(h_to + ((size_t)b * NCN + c) * DIM);
#define TROW(xr, row) { const float4* w4_ = (const float4*)(wm1b + (row) * HID + hoff); \
        fma4(t4[0], (xr), w4_[0]); fma4(t4[1], (xr), w4_[1]); \
        fma4(t4[2], (xr), w4_[2]); fma4(t4[3], (xr), w4_[3]); \
        fma4(t4[4], (xr), w4_[4]); }
#pragma unroll
        for (int q = 0; q < DIM / 4; q++) {
            float4 x = Xp[q];
            TROW(x.x, 4 * q + 0) TROW(x.y, 4 * q + 1)
            TROW(x.z, 4 * q + 2) TROW(x.w, 4 * q + 3)
        }
#undef TROW
#pragma unroll
        for (int jq = 0; jq < 5; jq++) {
            tp[2 * jq]     = (u32)f2bf(t4[jq].x) | ((u32)f2bf(t4[jq].y) << 16);
            tp[2 * jq + 1] = (u32)f2bf(t4[jq].z) | ((u32)f2bf(t4[jq].w) << 16);
        }
    }

    float s[20];
#pragma unroll
    for (int k = 0; k < 20; k++) s[k] = 0.f;

    int cn = cnt[c];
    cn = (cn < SLOT) ? cn : SLOT;
    const u16* efc = ef + c * SLOT;
    const char* Ubase = (const char*)U2h;
    int off16a = l8 * 16;
    int off8c = 256 + l8 * 8;

    int i = 0;
    int vA = (cn > 0) ? (int)efc[0] : 0;
    int vB = (cn > 1) ? (int)efc[1] : 0;

#define CONS8(W, base) { \
    s[(base) + 0] += fmaxf(bflo(W.x) + bflo(tp[(base) / 2 + 0]), 0.f); \
    s[(base) + 1] += fmaxf(bfhi(W.x) + bfhi(tp[(base) / 2 + 0]), 0.f); \
    s[(base) + 2] += fmaxf(bflo(W.y) + bflo(tp[(base) / 2 + 1]), 0.f); \
    s[(base) + 3] += fmaxf(bfhi(W.y) + bfhi(tp[(base) / 2 + 1]), 0.f); \
    s[(base) + 4] += fmaxf(bflo(W.z) + bflo(tp[(base) / 2 + 2]), 0.f); \
    s[(base) + 5] += fmaxf(bfhi(W.z) + bfhi(tp[(base) / 2 + 2]), 0.f); \
    s[(base) + 6] += fmaxf(bflo(W.w) + bflo(tp[(base) / 2 + 3]), 0.f); \
    s[(base) + 7] += fmaxf(bfhi(W.w) + bfhi(tp[(base) / 2 + 3]), 0.f); }
#define CONS4T(W) { \
    s[16] += fmaxf(bflo(W.x) + bflo(tp[8]), 0.f); \
    s[17] += fmaxf(bfhi(W.x) + bfhi(tp[8]), 0.f); \
    s[18] += fmaxf(bflo(W.y) + bflo(tp[9]), 0.f); \
    s[19] += fmaxf(bfhi(W.y) + bfhi(tp[9]), 0.f); }

    while (cn - i >= 2) {
        const char* pa = Ubase + (size_t)vA * 320;
        const char* pb = Ubase + (size_t)vB * 320;
        uint4 A0 = *(const uint4*)(pa + off16a);
        uint4 A1 = *(const uint4*)(pa + off16a + 128);
        uint2 A2 = *(const uint2*)(pa + off8c);
        uint4 B0 = *(const uint4*)(pb + off16a);
        uint4 B1 = *(const uint4*)(pb + off16a + 128);
        uint2 B2 = *(const uint2*)(pb + off8c);
        int nA = (i + 2 < cn) ? (int)efc[i + 2] : 0;
        int nB = (i + 3 < cn) ? (int)efc[i + 3] : 0;
        CONS8(A0, 0) CONS8(A1, 8) CONS4T(A2)
        CONS8(B0, 0) CONS8(B1, 8) CONS4T(B2)
        vA = nA; vB = nB; i += 2;
    }
    if (i < cn) {
        const char* pa = Ubase + (size_t)vA * 320;
        uint4 A0 = *(const uint4*)(pa + off16a);
        uint4 A1 = *(const uint4*)(pa + off16a + 128);
        uint2 A2 = *(const uint2*)(pa + off8c);
        CONS8(A0, 0) CONS8(A1, 8) CONS4T(A2)
    }
#undef CONS8
#undef CONS4T

    // ---- pack s -> bf16, interleaved 320B line per (side, c) ----
    u32 sp[10];
#pragma unroll
    for (int jq = 0; jq < 5; jq++) {
        sp[2 * jq]     = (u32)f2bf(s[4 * jq + 0]) | ((u32)f2bf(s[4 * jq + 1]) << 16);
        sp[2 * jq + 1] = (u32)f2bf(s[4 * jq + 2]) | ((u32)f2bf(s[4 * jq + 3]) << 16);
    }
    char* dst = (char*)s_buf + ((size_t)side * NCN + c) * 320;
    *(uint4*)(dst + off16a)       = make_uint4(sp[0], sp[1], sp[2], sp[3]);
    *(uint4*)(dst + off16a + 128) = make_uint4(sp[4], sp[5], sp[6], sp[7]);
    *(uint2*)(dst + off8c)        = make_uint2(sp[8], sp[9]);
}

// ------- aggB: dense per-node MLP (m = s@Wm2, a = relu(m@We1a + p), o = a@We2) -------
// Zero gathers -> latency-immune; VGPR can float. p computed inline from h_to+logit.

__global__ __launch_bounds__(256) void aggB_kernel(
        const u16* __restrict__ s_buf,
        const float* __restrict__ h_to_x, const float* __restrict__ h_to_z,
        const float* __restrict__ logit_x, const float* __restrict__ logit_z,
        const float* __restrict__ Wm2_x, const float* __restrict__ Wm2_z,
        const float* __restrict__ We1_x, const float* __restrict__ We1_z,
        const float* __restrict__ We2_x, const float* __restrict__ We2_z,
        float* __restrict__ out) {
    int side = blockIdx.x >> 10;
    const float* h_to = side ? h_to_z : h_to_x;
    const float* logit = side ? logit_z : logit_x;
    const float* Wm2 = side ? Wm2_z : Wm2_x;
    const float* We1 = side ? We1_z : We1_x;
    const float* We2 = side ? We2_z : We2_x;

    __shared__ __attribute__((aligned(16))) float wm2s[HID * MSGD];        // [40][20]
    __shared__ __attribute__((aligned(16))) float we1as[MSGD * HID];       // We1 rows 0..19
    __shared__ __attribute__((aligned(16))) float we1bs[DIM * HID];        // We1 rows 20..51
    __shared__ __attribute__((aligned(16))) float we1ls[HID + 8];          // We1 row 52
    __shared__ __attribute__((aligned(16))) float we2s[HID * WE2_STRIDE];  // [40][36]
    int tid = threadIdx.x;
    for (int i = tid; i < HID * MSGD; i += 256) { wm2s[i] = Wm2[i]; we1as[i] = We1[i]; }
    for (int i = tid; i < DIM * HID; i += 256) we1bs[i] = We1[MSGD * HID + i];
    for (int i = tid; i < HID * DIM; i += 256) {
        int h = i >> 5, d = i & 31;
        we2s[h * WE2_STRIDE + d] = We2[i];
    }
    if (tid < HID) we1ls[tid] = We1[(MSGD + DIM) * HID + tid];
    __syncthreads();

    int gt = (blockIdx.x & 1023) * 256 + tid;
    int c = gt >> 3;
    int l8 = gt & 7;
    int b = l8 & 3;
    int half = l8 >> 2;
    int hoff = half * 20;

    // ---- read s slice (20 bf16, interleaved layout) ----
    float s[20];
    {
        const char* sv = (const char*)s_buf + ((size_t)side * NCN + c) * 320;
        uint4 S0 = *(const uint4*)(sv + l8 * 16);
        uint4 S1 = *(const uint4*)(sv + 128 + l8 * 16);
        uint2 S2 = *(const uint2*)(sv + 256 + l8 * 8);
        s[0] = bflo(S0.x);  s[1] = bfhi(S0.x);  s[2] = bflo(S0.y);  s[3] = bfhi(S0.y);
        s[4] = bflo(S0.z);  s[5] = bfhi(S0.z);  s[6] = bflo(S0.w);  s[7] = bfhi(S0.w);
        s[8] = bflo(S1.x);  s[9] = bfhi(S1.x);  s[10] = bflo(S1.y); s[11] = bfhi(S1.y);
        s[12] = bflo(S1.z); s[13] = bfhi(S1.z); s[14] = bflo(S1.w); s[15] = bfhi(S1.w);
        s[16] = bflo(S2.x); s[17] = bfhi(S2.x); s[18] = bflo(S2.y); s[19] = bfhi(S2.y);
    }

    // ---- m partial: this lane's 20 h-rows of Wm2 ----
    float4 m4[5];
#pragma unroll
    for (int kq = 0; kq < 5; kq++) m4[kq] = make_float4(0.f, 0.f, 0.f, 0.f);
    const float* wmbase = wm2s + hoff * MSGD;
#define MROW(sv_, k) { const float4* w4_ = (const float4*)(wmbase + (k) * MSGD); \
    fma4(m4[0], (sv_), w4_[0]); fma4(m4[1], (sv_), w4_[1]); fma4(m4[2], (sv_), w4_[2]); \
    fma4(m4[3], (sv_), w4_[3]); fma4(m4[4], (sv_), w4_[4]); }
    MROW(s[0], 0)   MROW(s[1], 1)   MROW(s[2], 2)   MROW(s[3], 3)
    MROW(s[4], 4)   MROW(s[5], 5)   MROW(s[6], 6)   MROW(s[7], 7)
    MROW(s[8], 8)   MROW(s[9], 9)   MROW(s[10], 10) MROW(s[11], 11)
    MROW(s[12], 12) MROW(s[13], 13) MROW(s[14], 14) MROW(s[15], 15)
    MROW(s[16], 16) MROW(s[17], 17) MROW(s[18], 18) MROW(s[19], 19)
#undef MROW

    float mm[MSGD];
#pragma unroll
    for (int kq = 0; kq < 5; kq++) {
        mm[4 * kq + 0] = m4[kq].x; mm[4 * kq + 1] = m4[kq].y;
        mm[4 * kq + 2] = m4[kq].z; mm[4 * kq + 3] = m4[kq].w;
    }
#pragma unroll
    for (int k = 0; k < MSGD; k++) mm[k] += __shfl_xor(mm[k], 4);

    // ---- p inline: a = logit*we1l + X @ We1[20:52][:, hoff:] ----
    float4 a0, a1, a2, a3, a4;
    {
        float lg = logit[(size_t)b * NCN + c];
        const float4* wl = (const float4*)(we1ls + hoff);
        a0 = make_float4(lg * wl[0].x, lg * wl[0].y, lg * wl[0].z, lg * wl[0].w);
        a1 = make_float4(lg * wl[1].x, lg * wl[1].y, lg * wl[1].z, lg * wl[1].w);
        a2 = make_float4(lg * wl[2].x, lg * wl[2].y, lg * wl[2].z, lg * wl[2].w);
        a3 = make_float4(lg * wl[3].x, lg * wl[3].y, lg * wl[3].z, lg * wl[3].w);
        a4 = make_float4(lg * wl[4].x, lg * wl[4].y, lg * wl[4].z, lg * wl[4].w);
        const float4* Xp = (const float4*)(h_to + ((size_t)b * NCN + c) * DIM);
#define PROW(xr, row) { const float4* w4_ = (const float4*)(we1bs + (row) * HID + hoff); \
        fma4(a0, (xr), w4_[0]); fma4(a1, (xr), w4_[1]); fma4(a2, (xr), w4_[2]); \
        fma4(a3, (xr), w4_[3]); fma4(a4, (xr), w4_[4]); }
#pragma unroll
        for (int q = 0; q < DIM / 4; q++) {
            float4 x = Xp[q];
            PROW(x.x, 4 * q + 0) PROW(x.y, 4 * q + 1)
            PROW(x.z, 4 * q + 2) PROW(x.w, 4 * q + 3)
        }
#undef PROW
    }
    // a += mm @ We1[0:20]; relu
#pragma unroll
    for (int k = 0; k < MSGD; k++) {
        float mk = mm[k];
        const float4* w4 = (const float4*)(we1as + k * HID + hoff);
        fma4(a0, mk, w4[0]); fma4(a1, mk, w4[1]); fma4(a2, mk, w4[2]);
        fma4(a3, mk, w4[3]); fma4(a4, mk, w4[4]);
    }
    a0.x = fmaxf(a0.x, 0.f); a0.y = fmaxf(a0.y, 0.f); a0.z = fmaxf(a0.z, 0.f); a0.w = fmaxf(a0.w, 0.f);
    a1.x = fmaxf(a1.x, 0.f); a1.y = fmaxf(a1.y, 0.f); a1.z = fmaxf(a1.z, 0.f); a1.w = fmaxf(a1.w, 0.f);
    a2.x = fmaxf(a2.x, 0.f); a2.y = fmaxf(a2.y, 0.f); a2.z = fmaxf(a2.z, 0.f); a2.w = fmaxf(a2.w, 0.f);
    a3.x = fmaxf(a3.x, 0.f); a3.y = fmaxf(a3.y, 0.f); a3.z = fmaxf(a3.z, 0.f); a3.w = fmaxf(a3.w, 0.f);
    a4.x = fmaxf(a4.x, 0.f); a4.y = fmaxf(a4.y, 0.f); a4.z = fmaxf(a4.z, 0.f); a4.w = fmaxf(a4.w, 0.f);

    // ---- o partial: this lane's 20 h-rows of We2 ----
    float4 o4[8];
#pragma unroll
    for (int dq = 0; dq < 8; dq++) o4[dq] = make_float4(0.f, 0.f, 0.f, 0.f);
    const float* wobase = we2s + hoff * WE2_STRIDE;
#define OROW(av, k) { const float4* w4_ = (const float4*)(wobase + (k) * WE2_STRIDE); \
    fma4(o4[0], (av), w4_[0]); fma4(o4[1], (av), w4_[1]); fma4(o4[2], (av), w4_[2]); \
    fma4(o4[3], (av), w4_[3]); fma4(o4[4], (av), w4_[4]); fma4(o4[5], (av), w4_[5]); \
    fma4(o4[6], (av), w4_[6]); fma4(o4[7], (av), w4_[7]); }
    OROW(a0.x, 0)  OROW(a0.y, 1)  OROW(a0.z, 2)  OROW(a0.w, 3)
    OROW(a1.x, 4)  OROW(a1.y, 5)  OROW(a1.z, 6)  OROW(a1.w, 7)
    OROW(a2.x, 8)  OROW(a2.y, 9)  OROW(a2.z, 10) OROW(a2.w, 11)
    OROW(a3.x, 12) OROW(a3.y, 13) OROW(a3.z, 14) OROW(a3.w, 15)
    OROW(a4.x, 16) OROW(a4.y, 17) OROW(a4.z, 18) OROW(a4.w, 19)
#undef OROW

    float oo[DIM];
#pragma unroll
    for (int dq = 0; dq < 8; dq++) {
        oo[4 * dq + 0] = o4[dq].x; oo[4 * dq + 1] = o4[dq].y;
        oo[4 * dq + 2] = o4[dq].z; oo[4 * dq + 3] = o4[dq].w;
    }
#pragma unroll
    for (int d = 0; d < DIM; d++) oo[d] += __shfl_xor(oo[d], 4);

    float4* Orow = (float4*)(out + (size_t)side * (NB * NCN * DIM)
                                 + ((size_t)b * NCN + c) * DIM);
    if (half == 0) {
        Orow[0] = make_float4(oo[0], oo[1], oo[2], oo[3]);
        Orow[1] = make_float4(oo[4], oo[5], oo[6], oo[7]);
        Orow[2] = make_float4(oo[8], oo[9], oo[10], oo[11]);
        Orow[3] = make_float4(oo[12], oo[13], oo[14], oo[15]);
    } else {
        Orow[4] = make_float4(oo[16], oo[17], oo[18], oo[19]);
        Orow[5] = make_float4(oo[20], oo[21], oo[22], oo[23]);
        Orow[6] = make_float4(oo[24], oo[25], oo[26], oo[27]);
        Orow[7] = make_float4(oo[28], oo[29], oo[30], oo[31]);
    }
}

// ---------------- host ----------------

extern "C" void kernel_launch(void* const* d_in, const int* in_sizes, int n_in,
                              void* d_out, int out_size, void* d_ws, size_t ws_size,
                              hipStream_t stream) {
    const float* h_from   = (const float*)d_in[0];
    const float* h_to_x   = (const float*)d_in[1];
    const float* h_to_z   = (const float*)d_in[2];
    const float* hx_logit = (const float*)d_in[3];
    const float* hz_logit = (const float*)d_in[4];
    const int*   from_x   = (const int*)d_in[5];
    const int*   to_x     = (const int*)d_in[6];
    const int*   from_z   = (const int*)d_in[7];
    const int*   to_z     = (const int*)d_in[8];
    const float* Wm1_x    = (const float*)d_in[9];
    const float* Wm2_x    = (const float*)d_in[10];
    const float* Wm1_z    = (const float*)d_in[11];
    const float* Wm2_z    = (const float*)d_in[12];
    const float* We1_x    = (const float*)d_in[13];
    const float* We2_x    = (const float*)d_in[14];
    const float* We1_z    = (const float*)d_in[15];
    const float* We2_z    = (const float*)d_in[16];

    // Workspace layout (bytes), end = 68,419,584 (<= proven 85,328,128 budget)
    char* ws = (char*)d_ws;
    u16* U2h_x = (u16*)(ws);                       // 65536*320 = 20,971,520
    u16* U2h_z = (u16*)(ws + 20971520);            // 20,971,520
    u16* s_buf = (u16*)(ws + 41943040);            // 2*32768*320 = 20,971,520
    u16* ef_x  = (u16*)(ws + 62914560);            // 32768*40*2 = 2,621,440
    u16* ef_z  = (u16*)(ws + 65536000);            // 2,621,440
    int* cnt_x = (int*)(ws + 68157440);            // 131,072
    int* cnt_z = (int*)(ws + 68288512);            // 131,072
    float* out = (float*)d_out;

    hipMemsetAsync(ws + 68157440, 0, 262144, stream);  // zero cnt_x + cnt_z
    scatter_slot<<<2048, 256, 0, stream>>>(to_x, from_x, to_z, from_z,
                                           cnt_x, cnt_z, ef_x, ef_z);
    precompU_both<<<4096, 256, 0, stream>>>(h_from, Wm1_x, Wm1_z, U2h_x, U2h_z);
    aggA_kernel<<<2048, 256, 0, stream>>>(U2h_x, U2h_z, h_to_x, h_to_z,
                                          cnt_x, cnt_z, ef_x, ef_z,
                                          Wm1_x, Wm1_z, s_buf);
    aggB_kernel<<<2048, 256, 0, stream>>>(s_buf, h_to_x, h_to_z, hx_logit, hz_logit,
                                          Wm2_x, Wm2_z, We1_x, We1_z,
                                          We2_x, We2_z, out);
}

// Round 14
// 219.360 us; speedup vs baseline: 1.7646x; 1.7646x over previous
//
#include <hip/hip_runtime.h>

// Problem constants (from reference)
#define NVN 65536
#define NCN 32768
#define NB 4
#define DIM 32
#define NE 262144
#define HID 40
#define MSGD 20
#define SLOT 40        // edge slots per check node (Poisson(8) max-deg ~25 << 40)
#define WE2_STRIDE 36  // padded row stride for we2s (breaks h-row bank aliasing)

typedef unsigned short u16;
typedef unsigned int u32;

// bf16 helpers (RNE pack, cheap unpack)
__device__ __forceinline__ u16 f2bf(float f) {
    u32 u = __float_as_uint(f);
    u += 0x7fff + ((u >> 16) & 1);
    return (u16)(u >> 16);
}
__device__ __forceinline__ float bflo(u32 u) { return __uint_as_float(u << 16); }
__device__ __forceinline__ float bfhi(u32 u) { return __uint_as_float(u & 0xffff0000u); }

__device__ __forceinline__ void fma4(float4& acc, float a, const float4 w) {
    acc.x += a * w.x; acc.y += a * w.y; acc.z += a * w.z; acc.w += a * w.w;
}

// ---------------- direct slot-scatter (replaces hist+scan+scatter) ----------------

__global__ __launch_bounds__(256) void scatter_slot(const int* __restrict__ to_x,
                                                    const int* __restrict__ from_x,
                                                    const int* __restrict__ to_z,
                                                    const int* __restrict__ from_z,
                                                    int* __restrict__ cnt_x,
                                                    int* __restrict__ cnt_z,
                                                    u16* __restrict__ ef_x,
                                                    u16* __restrict__ ef_z) {
    int bid = blockIdx.x;
    int e = (bid & 1023) * 256 + threadIdx.x;
    const int* t; const int* f; int* cnt; u16* ef;
    if (bid < 1024) { t = to_x; f = from_x; cnt = cnt_x; ef = ef_x; }
    else            { t = to_z; f = from_z; cnt = cnt_z; ef = ef_z; }
    int c = t[e];
    int pos = atomicAdd(&cnt[c], 1);
    if (pos < SLOT) ef[c * SLOT + pos] = (u16)f[e];
}

// ------- Precompute U2h, BOTH sides, 20 outputs/thread, LANE-INTERLEAVED layout -------
// Per v: 320B line; lane l8's 20 bf16 live at {v*320 + l8*16, +128+l8*16, +256+l8*8}.

__global__ __launch_bounds__(256) void precompU_both(const float* __restrict__ h_from,
                                                     const float* __restrict__ Wm1_x,
                                                     const float* __restrict__ Wm1_z,
                                                     u16* __restrict__ U2h_x,
                                                     u16* __restrict__ U2h_z) {
    int side = blockIdx.x >> 11;
    const float* Wm1 = side ? Wm1_z : Wm1_x;
    u16* U2h = side ? U2h_z : U2h_x;

    __shared__ __attribute__((aligned(16))) float w[DIM * HID];
    int tid = threadIdx.x;
    for (int i = tid; i < DIM * HID; i += 256) w[i] = Wm1[i];
    __syncthreads();

    int gt = (blockIdx.x & 2047) * 256 + tid;
    int v = gt >> 3;
    int l8 = gt & 7;
    int b = l8 & 3;
    int hoff = (l8 >> 2) * 20;

    const float4* hf4 = (const float4*)(h_from + ((size_t)b * NVN + v) * DIM);
    float4 acc4[5];
#pragma unroll
    for (int jq = 0; jq < 5; jq++) acc4[jq] = make_float4(0.f, 0.f, 0.f, 0.f);
#pragma unroll
    for (int q = 0; q < DIM / 4; q++) {
        float4 x = hf4[q];
#define WROW(xr, row) { const float4* w4_ = (const float4*)(w + (row) * HID + hoff); \
        fma4(acc4[0], (xr), w4_[0]); fma4(acc4[1], (xr), w4_[1]); \
        fma4(acc4[2], (xr), w4_[2]); fma4(acc4[3], (xr), w4_[3]); \
        fma4(acc4[4], (xr), w4_[4]); }
        WROW(x.x, 4 * q + 0) WROW(x.y, 4 * q + 1) WROW(x.z, 4 * q + 2) WROW(x.w, 4 * q + 3)
#undef WROW
    }
    u32 p[10];
#pragma unroll
    for (int jq = 0; jq < 5; jq++) {
        p[2 * jq]     = (u32)f2bf(acc4[jq].x) | ((u32)f2bf(acc4[jq].y) << 16);
        p[2 * jq + 1] = (u32)f2bf(acc4[jq].z) | ((u32)f2bf(acc4[jq].w) << 16);
    }
    char* dst = (char*)U2h + (size_t)v * 320;
    *(uint4*)(dst + l8 * 16)       = make_uint4(p[0], p[1], p[2], p[3]);
    *(uint4*)(dst + 128 + l8 * 16) = make_uint4(p[4], p[5], p[6], p[7]);
    *(uint2*)(dst + 256 + l8 * 8)  = make_uint2(p[8], p[9]);
}

// ------- Precompute T (only) bf16, BOTH sides, 20 out/thread, interleaved layout -------
// P is NOT staged: aggB computes it inline (latency-immune kernel, VGPR free to float).

__global__ __launch_bounds__(256) void precompT_both(
        const float* __restrict__ h_to_x, const float* __restrict__ h_to_z,
        const float* __restrict__ Wm1_x, const float* __restrict__ Wm1_z,
        u16* __restrict__ ts_x, u16* __restrict__ ts_z) {
    int side = blockIdx.x >> 10;
    const float* h_to = side ? h_to_z : h_to_x;
    const float* Wm1 = side ? Wm1_z : Wm1_x;
    u16* ts = side ? ts_z : ts_x;

    __shared__ __attribute__((aligned(16))) float wm1b[DIM * HID];  // Wm1 rows 32..63
    int tid = threadIdx.x;
    for (int i = tid; i < DIM * HID; i += 256) wm1b[i] = Wm1[DIM * HID + i];
    __syncthreads();

    int gt = (blockIdx.x & 1023) * 256 + tid;
    int c = gt >> 3;
    int l8 = gt & 7;
    int b = l8 & 3;
    int hoff = (l8 >> 2) * 20;

    const float4* h4 = (const float4*)(h_to + ((size_t)b * NCN + c) * DIM);
    float4 acc4[5];
#pragma unroll
    for (int jq = 0; jq < 5; jq++) acc4[jq] = make_float4(0.f, 0.f, 0.f, 0.f);
#pragma unroll
    for (int q = 0; q < DIM / 4; q++) {
        float4 x = h4[q];
#define WROW(xr, row) { const float4* w4_ = (const float4*)(wm1b + (row) * HID + hoff); \
        fma4(acc4[0], (xr), w4_[0]); fma4(acc4[1], (xr), w4_[1]); \
        fma4(acc4[2], (xr), w4_[2]); fma4(acc4[3], (xr), w4_[3]); \
        fma4(acc4[4], (xr), w4_[4]); }
        WROW(x.x, 4 * q + 0) WROW(x.y, 4 * q + 1) WROW(x.z, 4 * q + 2) WROW(x.w, 4 * q + 3)
#undef WROW
    }
    u32 p[10];
#pragma unroll
    for (int jq = 0; jq < 5; jq++) {
        p[2 * jq]     = (u32)f2bf(acc4[jq].x) | ((u32)f2bf(acc4[jq].y) << 16);
        p[2 * jq + 1] = (u32)f2bf(acc4[jq].z) | ((u32)f2bf(acc4[jq].w) << 16);
    }
    char* dst = (char*)ts + (size_t)c * 320;
    *(uint4*)(dst + l8 * 16)       = make_uint4(p[0], p[1], p[2], p[3]);
    *(uint4*)(dst + 128 + l8 * 16) = make_uint4(p[4], p[5], p[6], p[7]);
    *(uint2*)(dst + 256 + l8 * 8)  = make_uint2(p[8], p[9]);
}

// ------- aggA: pure gather+relu-sum, BOTH sides. NO LDS, NO matvec. -------
// r9+r13 lesson: fusing any LDS-weight matvec into the gather kernel explodes
// VGPR to 256 + scratch spill. Here: T read PACKED (10 u32) from staging, s[20]
// f32, one 3-load bank + index prefetch. Live ~50 regs -> forced 8 waves/SIMD
// via launch_bounds(256,8) (the VGPR<=64 cliff; m69). s overwrites the T line
// in place (T consumed exactly once, by this thread; single pointer, no alias UB).

__global__ __launch_bounds__(256, 8) void aggA_kernel(
        const u16* __restrict__ U2h_x, const u16* __restrict__ U2h_z,
        u16* __restrict__ ts_x, u16* __restrict__ ts_z,
        const int* __restrict__ cnt_x, const int* __restrict__ cnt_z,
        const u16* __restrict__ ef_x, const u16* __restrict__ ef_z) {
    int side = blockIdx.x >> 10;
    const char* Ubase = (const char*)(side ? U2h_z : U2h_x);
    char* ts = (char*)(side ? ts_z : ts_x);
    const int* cnt = side ? cnt_z : cnt_x;
    const u16* ef = side ? ef_z : ef_x;

    int gt = (blockIdx.x & 1023) * 256 + threadIdx.x;
    int c = gt >> 3;
    int l8 = gt & 7;
    int off16a = l8 * 16;
    int off8c = 256 + l8 * 8;

    char* tline = ts + (size_t)c * 320;
    uint4 T0 = *(const uint4*)(tline + off16a);
    uint4 T1 = *(const uint4*)(tline + off16a + 128);
    uint2 Tc = *(const uint2*)(tline + off8c);

    float s[20];
#pragma unroll
    for (int k = 0; k < 20; k++) s[k] = 0.f;

    int cn = cnt[c];
    cn = (cn < SLOT) ? cn : SLOT;
    const u16* efc = ef + c * SLOT;

    int vA = (cn > 0) ? (int)efc[0] : 0;
#define ACC(su, aw, tw) { \
    s[su]     += fmaxf(bflo(aw) + bflo(tw), 0.f); \
    s[(su)+1] += fmaxf(bfhi(aw) + bfhi(tw), 0.f); }
    for (int i = 0; i < cn; ++i) {
        const char* pa = Ubase + (size_t)vA * 320;
        uint4 A0 = *(const uint4*)(pa + off16a);
        uint4 A1 = *(const uint4*)(pa + off16a + 128);
        uint2 A2 = *(const uint2*)(pa + off8c);
        vA = (i + 1 < cn) ? (int)efc[i + 1] : 0;
        ACC(0, A0.x, T0.x)  ACC(2, A0.y, T0.y)  ACC(4, A0.z, T0.z)  ACC(6, A0.w, T0.w)
        ACC(8, A1.x, T1.x)  ACC(10, A1.y, T1.y) ACC(12, A1.z, T1.z) ACC(14, A1.w, T1.w)
        ACC(16, A2.x, Tc.x) ACC(18, A2.y, Tc.y)
    }
#undef ACC

    // pack s -> bf16, overwrite the T line (consumed above; aggB reads this as s)
    u32 sp[10];
#pragma unroll
    for (int jq = 0; jq < 5; jq++) {
        sp[2 * jq]     = (u32)f2bf(s[4 * jq + 0]) | ((u32)f2bf(s[4 * jq + 1]) << 16);
        sp[2 * jq + 1] = (u32)f2bf(s[4 * jq + 2]) | ((u32)f2bf(s[4 * jq + 3]) << 16);
    }
    *(uint4*)(tline + off16a)       = make_uint4(sp[0], sp[1], sp[2], sp[3]);
    *(uint4*)(tline + off16a + 128) = make_uint4(sp[4], sp[5], sp[6], sp[7]);
    *(uint2*)(tline + off8c)        = make_uint2(sp[8], sp[9]);
}

// ------- aggB: dense per-node MLP (m = s@Wm2, a = relu(m@We1a + p), o = a@We2) -------
// Zero gathers -> latency-immune; VGPR can float. p computed inline from h_to+logit.

__global__ __launch_bounds__(256) void aggB_kernel(
        const u16* __restrict__ ts_x, const u16* __restrict__ ts_z,
        const float* __restrict__ h_to_x, const float* __restrict__ h_to_z,
        const float* __restrict__ logit_x, const float* __restrict__ logit_z,
        const float* __restrict__ Wm2_x, const float* __restrict__ Wm2_z,
        const float* __restrict__ We1_x, const float* __restrict__ We1_z,
        const float* __restrict__ We2_x, const float* __restrict__ We2_z,
        float* __restrict__ out) {
    int side = blockIdx.x >> 10;
    const u16* ts = side ? ts_z : ts_x;
    const float* h_to = side ? h_to_z : h_to_x;
    const float* logit = side ? logit_z : logit_x;
    const float* Wm2 = side ? Wm2_z : Wm2_x;
    const float* We1 = side ? We1_z : We1_x;
    const float* We2 = side ? We2_z : We2_x;

    __shared__ __attribute__((aligned(16))) float wm2s[HID * MSGD];        // [40][20]
    __shared__ __attribute__((aligned(16))) float we1as[MSGD * HID];       // We1 rows 0..19
    __shared__ __attribute__((aligned(16))) float we1bs[DIM * HID];        // We1 rows 20..51
    __shared__ __attribute__((aligned(16))) float we1ls[HID + 8];          // We1 row 52
    __shared__ __attribute__((aligned(16))) float we2s[HID * WE2_STRIDE];  // [40][36]
    int tid = threadIdx.x;
    for (int i = tid; i < HID * MSGD; i += 256) { wm2s[i] = Wm2[i]; we1as[i] = We1[i]; }
    for (int i = tid; i < DIM * HID; i += 256) we1bs[i] = We1[MSGD * HID + i];
    for (int i = tid; i < HID * DIM; i += 256) {
        int h = i >> 5, d = i & 31;
        we2s[h * WE2_STRIDE + d] = We2[i];
    }
    if (tid < HID) we1ls[tid] = We1[(MSGD + DIM) * HID + tid];
    __syncthreads();

    int gt = (blockIdx.x & 1023) * 256 + tid;
    int c = gt >> 3;
    int l8 = gt & 7;
    int b = l8 & 3;
    int half = l8 >> 2;
    int hoff = half * 20;

    // ---- read s slice (20 bf16, interleaved layout; ts was overwritten by aggA) ----
    float s[20];
    {
        const char* sv = (const char*)ts + (size_t)c * 320;
        uint4 S0 = *(const uint4*)(sv + l8 * 16);
        uint4 S1 = *(const uint4*)(sv + 128 + l8 * 16);
        uint2 S2 = *(const uint2*)(sv + 256 + l8 * 8);
        s[0] = bflo(S0.x);  s[1] = bfhi(S0.x);  s[2] = bflo(S0.y);  s[3] = bfhi(S0.y);
        s[4] = bflo(S0.z);  s[5] = bfhi(S0.z);  s[6] = bflo(S0.w);  s[7] = bfhi(S0.w);
        s[8] = bflo(S1.x);  s[9] = bfhi(S1.x);  s[10] = bflo(S1.y); s[11] = bfhi(S1.y);
        s[12] = bflo(S1.z); s[13] = bfhi(S1.z); s[14] = bflo(S1.w); s[15] = bfhi(S1.w);
        s[16] = bflo(S2.x); s[17] = bfhi(S2.x); s[18] = bflo(S2.y); s[19] = bfhi(S2.y);
    }

    // ---- m partial: this lane's 20 h-rows of Wm2 ----
    float4 m4[5];
#pragma unroll
    for (int kq = 0; kq < 5; kq++) m4[kq] = make_float4(0.f, 0.f, 0.f, 0.f);
    const float* wmbase = wm2s + hoff * MSGD;
#define MROW(sv_, k) { const float4* w4_ = (const float4*)(wmbase + (k) * MSGD); \
    fma4(m4[0], (sv_), w4_[0]); fma4(m4[1], (sv_), w4_[1]); fma4(m4[2], (sv_), w4_[2]); \
    fma4(m4[3], (sv_), w4_[3]); fma4(m4[4], (sv_), w4_[4]); }
    MROW(s[0], 0)   MROW(s[1], 1)   MROW(s[2], 2)   MROW(s[3], 3)
    MROW(s[4], 4)   MROW(s[5], 5)   MROW(s[6], 6)   MROW(s[7], 7)
    MROW(s[8], 8)   MROW(s[9], 9)   MROW(s[10], 10) MROW(s[11], 11)
    MROW(s[12], 12) MROW(s[13], 13) MROW(s[14], 14) MROW(s[15], 15)
    MROW(s[16], 16) MROW(s[17], 17) MROW(s[18], 18) MROW(s[19], 19)
#undef MROW

    float mm[MSGD];
#pragma unroll
    for (int kq = 0; kq < 5; kq++) {
        mm[4 * kq + 0] = m4[kq].x; mm[4 * kq + 1] = m4[kq].y;
        mm[4 * kq + 2] = m4[kq].z; mm[4 * kq + 3] = m4[kq].w;
    }
#pragma unroll
    for (int k = 0; k < MSGD; k++) mm[k] += __shfl_xor(mm[k], 4);

    // ---- p inline: a = logit*we1l + X @ We1[20:52][:, hoff:] ----
    float4 a0, a1, a2, a3, a4;
    {
        float lg = logit[(size_t)b * NCN + c];
        const float4* wl = (const float4*)(we1ls + hoff);
        a0 = make_float4(lg * wl[0].x, lg * wl[0].y, lg * wl[0].z, lg * wl[0].w);
        a1 = make_float4(lg * wl[1].x, lg * wl[1].y, lg * wl[1].z, lg * wl[1].w);
        a2 = make_float4(lg * wl[2].x, lg * wl[2].y, lg * wl[2].z, lg * wl[2].w);
        a3 = make_float4(lg * wl[3].x, lg * wl[3].y, lg * wl[3].z, lg * wl[3].w);
        a4 = make_float4(lg * wl[4].x, lg * wl[4].y, lg * wl[4].z, lg * wl[4].w);
        const float4* Xp = (const float4*)(h_to + ((size_t)b * NCN + c) * DIM);
#define PROW(xr, row) { const float4* w4_ = (const float4*)(we1bs + (row) * HID + hoff); \
        fma4(a0, (xr), w4_[0]); fma4(a1, (xr), w4_[1]); fma4(a2, (xr), w4_[2]); \
        fma4(a3, (xr), w4_[3]); fma4(a4, (xr), w4_[4]); }
#pragma unroll
        for (int q = 0; q < DIM / 4; q++) {
            float4 x = Xp[q];
            PROW(x.x, 4 * q + 0) PROW(x.y, 4 * q + 1)
            PROW(x.z, 4 * q + 2) PROW(x.w, 4 * q + 3)
        }
#undef PROW
    }
#pragma unroll
    for (int k = 0; k < MSGD; k++) {
        float mk = mm[k];
        const float4* w4 = (const float4*)(we1as + k * HID + hoff);
        fma4(a0, mk, w4[0]); fma4(a1, mk, w4[1]); fma4(a2, mk, w4[2]);
        fma4(a3, mk, w4[3]); fma4(a4, mk, w4[4]);
    }
    a0.x = fmaxf(a0.x, 0.f); a0.y = fmaxf(a0.y, 0.f); a0.z = fmaxf(a0.z, 0.f); a0.w = fmaxf(a0.w, 0.f);
    a1.x = fmaxf(a1.x, 0.f); a1.y = fmaxf(a1.y, 0.f); a1.z = fmaxf(a1.z, 0.f); a1.w = fmaxf(a1.w, 0.f);
    a2.x = fmaxf(a2.x, 0.f); a2.y = fmaxf(a2.y, 0.f); a2.z = fmaxf(a2.z, 0.f); a2.w = fmaxf(a2.w, 0.f);
    a3.x = fmaxf(a3.x, 0.f); a3.y = fmaxf(a3.y, 0.f); a3.z = fmaxf(a3.z, 0.f); a3.w = fmaxf(a3.w, 0.f);
    a4.x = fmaxf(a4.x, 0.f); a4.y = fmaxf(a4.y, 0.f); a4.z = fmaxf(a4.z, 0.f); a4.w = fmaxf(a4.w, 0.f);

    // ---- o partial: this lane's 20 h-rows of We2 ----
    float4 o4[8];
#pragma unroll
    for (int dq = 0; dq < 8; dq++) o4[dq] = make_float4(0.f, 0.f, 0.f, 0.f);
    const float* wobase = we2s + hoff * WE2_STRIDE;
#define OROW(av, k) { const float4* w4_ = (const float4*)(wobase + (k) * WE2_STRIDE); \
    fma4(o4[0], (av), w4_[0]); fma4(o4[1], (av), w4_[1]); fma4(o4[2], (av), w4_[2]); \
    fma4(o4[3], (av), w4_[3]); fma4(o4[4], (av), w4_[4]); fma4(o4[5], (av), w4_[5]); \
    fma4(o4[6], (av), w4_[6]); fma4(o4[7], (av), w4_[7]); }
    OROW(a0.x, 0)  OROW(a0.y, 1)  OROW(a0.z, 2)  OROW(a0.w, 3)
    OROW(a1.x, 4)  OROW(a1.y, 5)  OROW(a1.z, 6)  OROW(a1.w, 7)
    OROW(a2.x, 8)  OROW(a2.y, 9)  OROW(a2.z, 10) OROW(a2.w, 11)
    OROW(a3.x, 12) OROW(a3.y, 13) OROW(a3.z, 14) OROW(a3.w, 15)
    OROW(a4.x, 16) OROW(a4.y, 17) OROW(a4.z, 18) OROW(a4.w, 19)
#undef OROW

    float oo[DIM];
#pragma unroll
    for (int dq = 0; dq < 8; dq++) {
        oo[4 * dq + 0] = o4[dq].x; oo[4 * dq + 1] = o4[dq].y;
        oo[4 * dq + 2] = o4[dq].z; oo[4 * dq + 3] = o4[dq].w;
    }
#pragma unroll
    for (int d = 0; d < DIM; d++) oo[d] += __shfl_xor(oo[d], 4);

    float4* Orow = (float4*)(out + (size_t)side * (NB * NCN * DIM)
                                 + ((size_t)b * NCN + c) * DIM);
    if (half == 0) {
        Orow[0] = make_float4(oo[0], oo[1], oo[2], oo[3]);
        Orow[1] = make_float4(oo[4], oo[5], oo[6], oo[7]);
        Orow[2] = make_float4(oo[8], oo[9], oo[10], oo[11]);
        Orow[3] = make_float4(oo[12], oo[13], oo[14], oo[15]);
    } else {
        Orow[4] = make_float4(oo[16], oo[17], oo[18], oo[19]);
        Orow[5] = make_float4(oo[20], oo[21], oo[22], oo[23]);
        Orow[6] = make_float4(oo[24], oo[25], oo[26], oo[27]);
        Orow[7] = make_float4(oo[28], oo[29], oo[30], oo[31]);
    }
}

// ---------------- host ----------------

extern "C" void kernel_launch(void* const* d_in, const int* in_sizes, int n_in,
                              void* d_out, int out_size, void* d_ws, size_t ws_size,
                              hipStream_t stream) {
    const float* h_from   = (const float*)d_in[0];
    const float* h_to_x   = (const float*)d_in[1];
    const float* h_to_z   = (const float*)d_in[2];
    const float* hx_logit = (const float*)d_in[3];
    const float* hz_logit = (const float*)d_in[4];
    const int*   from_x   = (const int*)d_in[5];
    const int*   to_x     = (const int*)d_in[6];
    const int*   from_z   = (const int*)d_in[7];
    const int*   to_z     = (const int*)d_in[8];
    const float* Wm1_x    = (const float*)d_in[9];
    const float* Wm2_x    = (const float*)d_in[10];
    const float* Wm1_z    = (const float*)d_in[11];
    const float* Wm2_z    = (const float*)d_in[12];
    const float* We1_x    = (const float*)d_in[13];
    const float* We2_x    = (const float*)d_in[14];
    const float* We1_z    = (const float*)d_in[15];
    const float* We2_z    = (const float*)d_in[16];

    // Workspace layout (bytes), end = 68,419,584 (<= proven 85,328,128 budget)
    char* ws = (char*)d_ws;
    u16* U2h_x = (u16*)(ws);                       // 65536*320 = 20,971,520
    u16* U2h_z = (u16*)(ws + 20971520);            // 20,971,520
    u16* ts_x  = (u16*)(ws + 41943040);            // 32768*320 = 10,485,760 (T, then s)
    u16* ts_z  = (u16*)(ws + 52428800);            // 10,485,760
    u16* ef_x  = (u16*)(ws + 62914560);            // 32768*40*2 = 2,621,440
    u16* ef_z  = (u16*)(ws + 65536000);            // 2,621,440
    int* cnt_x = (int*)(ws + 68157440);            // 131,072
    int* cnt_z = (int*)(ws + 68288512);            // 131,072
    float* out = (float*)d_out;

    hipMemsetAsync(ws + 68157440, 0, 262144, stream);  // zero cnt_x + cnt_z
    scatter_slot<<<2048, 256, 0, stream>>>(to_x, from_x, to_z, from_z,
                                           cnt_x, cnt_z, ef_x, ef_z);
    precompU_both<<<4096, 256, 0, stream>>>(h_from, Wm1_x, Wm1_z, U2h_x, U2h_z);
    precompT_both<<<2048, 256, 0, stream>>>(h_to_x, h_to_z, Wm1_x, Wm1_z, ts_x, ts_z);
    aggA_kernel<<<2048, 256, 0, stream>>>(U2h_x, U2h_z, ts_x, ts_z,
                                          cnt_x, cnt_z, ef_x, ef_z);
    aggB_kernel<<<2048, 256, 0, stream>>>(ts_x, ts_z, h_to_x, h_to_z,
                                          hx_logit, hz_logit,
                                          Wm2_x, Wm2_z, We1_x, We1_z,
                                          We2_x, We2_z, out);
}

// Round 15
// 218.377 us; speedup vs baseline: 1.7726x; 1.0045x over previous
//
#include <hip/hip_runtime.h>

// Problem constants (from reference)
#define NVN 65536
#define NCN 32768
#define NB 4
#define DIM 32
#define NE 262144
#define HID 40
#define MSGD 20
#define SLOT 40        // edge slots per check node (Poisson(8) max-deg ~25 << 40)

typedef unsigned short u16;
typedef unsigned int u32;

// bf16 helpers (RNE pack, cheap unpack)
__device__ __forceinline__ u16 f2bf(float f) {
    u32 u = __float_as_uint(f);
    u += 0x7fff + ((u >> 16) & 1);
    return (u16)(u >> 16);
}
__device__ __forceinline__ float bflo(u32 u) { return __uint_as_float(u << 16); }
__device__ __forceinline__ float bfhi(u32 u) { return __uint_as_float(u & 0xffff0000u); }

// acc.{x..w} += a * w[0..3]  (w is a WAVE-UNIFORM pointer -> s_load + SGPR operand)
#define SFMA4(acc, a, wp) { (acc).x += (a) * (wp)[0]; (acc).y += (a) * (wp)[1]; \
                            (acc).z += (a) * (wp)[2]; (acc).w += (a) * (wp)[3]; }

// ---------------- direct slot-scatter ----------------

__global__ __launch_bounds__(256) void scatter_slot(const int* __restrict__ to_x,
                                                    const int* __restrict__ from_x,
                                                    const int* __restrict__ to_z,
                                                    const int* __restrict__ from_z,
                                                    int* __restrict__ cnt_x,
                                                    int* __restrict__ cnt_z,
                                                    u16* __restrict__ ef_x,
                                                    u16* __restrict__ ef_z) {
    int bid = blockIdx.x;
    int e = (bid & 1023) * 256 + threadIdx.x;
    const int* t; const int* f; int* cnt; u16* ef;
    if (bid < 1024) { t = to_x; f = from_x; cnt = cnt_x; ef = ef_x; }
    else            { t = to_z; f = from_z; cnt = cnt_z; ef = ef_z; }
    int c = t[e];
    int pos = atomicAdd(&cnt[c], 1);
    if (pos < SLOT) ef[c * SLOT + pos] = (u16)f[e];
}

// ------- precompU: BOTH sides, scalar weights (wave-uniform hoff), no LDS -------
// thread = (side, v, b, half): half is PER-WAVE uniform (tid>>7, readfirstlane).
// Output layout per v: 320B line, chunk ch=half*4+b at {ch*16, 128+ch*16, 256+ch*8}.

__global__ __launch_bounds__(256) void precompU_both(const float* __restrict__ h_from,
                                                     const float* __restrict__ Wm1_x,
                                                     const float* __restrict__ Wm1_z,
                                                     u16* __restrict__ U2h_x,
                                                     u16* __restrict__ U2h_z) {
    int side = blockIdx.x >> 11;
    const float* __restrict__ Wm1 = side ? Wm1_z : Wm1_x;
    u16* U2h = side ? U2h_z : U2h_x;

    int tid = threadIdx.x;
    int half = tid >> 7;
    int hoff = __builtin_amdgcn_readfirstlane(half * 20);
    int lane = tid & 63;
    int sub = (tid >> 6) & 1;
    int b = lane & 3;
    int vloc = sub * 16 + (lane >> 2);
    int v = (blockIdx.x & 2047) * 32 + vloc;
    int ch = half * 4 + b;

    const float4* hf4 = (const float4*)(h_from + ((size_t)b * NVN + v) * DIM);
    float4 acc4[5];
#pragma unroll
    for (int jq = 0; jq < 5; jq++) acc4[jq] = make_float4(0.f, 0.f, 0.f, 0.f);
#pragma unroll
    for (int q = 0; q < DIM / 4; q++) {
        float4 x = hf4[q];
#define WROW(xr, row) { const float* wr = Wm1 + (row) * HID + hoff; \
        SFMA4(acc4[0], (xr), wr) SFMA4(acc4[1], (xr), wr + 4) SFMA4(acc4[2], (xr), wr + 8) \
        SFMA4(acc4[3], (xr), wr + 12) SFMA4(acc4[4], (xr), wr + 16) }
        WROW(x.x, 4 * q + 0) WROW(x.y, 4 * q + 1) WROW(x.z, 4 * q + 2) WROW(x.w, 4 * q + 3)
#undef WROW
    }
    u32 p[10];
#pragma unroll
    for (int jq = 0; jq < 5; jq++) {
        p[2 * jq]     = (u32)f2bf(acc4[jq].x) | ((u32)f2bf(acc4[jq].y) << 16);
        p[2 * jq + 1] = (u32)f2bf(acc4[jq].z) | ((u32)f2bf(acc4[jq].w) << 16);
    }
    char* dst = (char*)U2h + (size_t)v * 320;
    *(uint4*)(dst + ch * 16)       = make_uint4(p[0], p[1], p[2], p[3]);
    *(uint4*)(dst + 128 + ch * 16) = make_uint4(p[4], p[5], p[6], p[7]);
    *(uint2*)(dst + 256 + ch * 8)  = make_uint2(p[8], p[9]);
}

// ------- precompT: BOTH sides, scalar weights (Wm1 rows 32..63), no LDS -------

__global__ __launch_bounds__(256) void precompT_both(
        const float* __restrict__ h_to_x, const float* __restrict__ h_to_z,
        const float* __restrict__ Wm1_x, const float* __restrict__ Wm1_z,
        u16* __restrict__ ts_x, u16* __restrict__ ts_z) {
    int side = blockIdx.x >> 10;
    const float* __restrict__ h_to = side ? h_to_z : h_to_x;
    const float* __restrict__ Wm1 = side ? Wm1_z : Wm1_x;
    u16* ts = side ? ts_z : ts_x;

    int tid = threadIdx.x;
    int half = tid >> 7;
    int hoff = __builtin_amdgcn_readfirstlane(half * 20);
    int lane = tid & 63;
    int sub = (tid >> 6) & 1;
    int b = lane & 3;
    int cloc = sub * 16 + (lane >> 2);
    int c = (blockIdx.x & 1023) * 32 + cloc;
    int ch = half * 4 + b;

    const float4* h4 = (const float4*)(h_to + ((size_t)b * NCN + c) * DIM);
    float4 acc4[5];
#pragma unroll
    for (int jq = 0; jq < 5; jq++) acc4[jq] = make_float4(0.f, 0.f, 0.f, 0.f);
#pragma unroll
    for (int q = 0; q < DIM / 4; q++) {
        float4 x = h4[q];
#define WROW(xr, row) { const float* wr = Wm1 + (DIM + (row)) * HID + hoff; \
        SFMA4(acc4[0], (xr), wr) SFMA4(acc4[1], (xr), wr + 4) SFMA4(acc4[2], (xr), wr + 8) \
        SFMA4(acc4[3], (xr), wr + 12) SFMA4(acc4[4], (xr), wr + 16) }
        WROW(x.x, 4 * q + 0) WROW(x.y, 4 * q + 1) WROW(x.z, 4 * q + 2) WROW(x.w, 4 * q + 3)
#undef WROW
    }
    u32 p[10];
#pragma unroll
    for (int jq = 0; jq < 5; jq++) {
        p[2 * jq]     = (u32)f2bf(acc4[jq].x) | ((u32)f2bf(acc4[jq].y) << 16);
        p[2 * jq + 1] = (u32)f2bf(acc4[jq].z) | ((u32)f2bf(acc4[jq].w) << 16);
    }
    char* dst = (char*)ts + (size_t)c * 320;
    *(uint4*)(dst + ch * 16)       = make_uint4(p[0], p[1], p[2], p[3]);
    *(uint4*)(dst + 128 + ch * 16) = make_uint4(p[4], p[5], p[6], p[7]);
    *(uint2*)(dst + 256 + ch * 8)  = make_uint2(p[8], p[9]);
}

// ------- aggA: pure gather+relu-sum, BOTH sides. UNCHANGED from r14 (fast). -------

__global__ __launch_bounds__(256, 8) void aggA_kernel(
        const u16* __restrict__ U2h_x, const u16* __restrict__ U2h_z,
        u16* __restrict__ ts_x, u16* __restrict__ ts_z,
        const int* __restrict__ cnt_x, const int* __restrict__ cnt_z,
        const u16* __restrict__ ef_x, const u16* __restrict__ ef_z) {
    int side = blockIdx.x >> 10;
    const char* Ubase = (const char*)(side ? U2h_z : U2h_x);
    char* ts = (char*)(side ? ts_z : ts_x);
    const int* cnt = side ? cnt_z : cnt_x;
    const u16* ef = side ? ef_z : ef_x;

    int gt = (blockIdx.x & 1023) * 256 + threadIdx.x;
    int c = gt >> 3;
    int l8 = gt & 7;
    int off16a = l8 * 16;
    int off8c = 256 + l8 * 8;

    char* tline = ts + (size_t)c * 320;
    uint4 T0 = *(const uint4*)(tline + off16a);
    uint4 T1 = *(const uint4*)(tline + off16a + 128);
    uint2 Tc = *(const uint2*)(tline + off8c);

    float s[20];
#pragma unroll
    for (int k = 0; k < 20; k++) s[k] = 0.f;

    int cn = cnt[c];
    cn = (cn < SLOT) ? cn : SLOT;
    const u16* efc = ef + c * SLOT;

    int vA = (cn > 0) ? (int)efc[0] : 0;
#define ACC(su, aw, tw) { \
    s[su]     += fmaxf(bflo(aw) + bflo(tw), 0.f); \
    s[(su)+1] += fmaxf(bfhi(aw) + bfhi(tw), 0.f); }
    for (int i = 0; i < cn; ++i) {
        const char* pa = Ubase + (size_t)vA * 320;
        uint4 A0 = *(const uint4*)(pa + off16a);
        uint4 A1 = *(const uint4*)(pa + off16a + 128);
        uint2 A2 = *(const uint2*)(pa + off8c);
        vA = (i + 1 < cn) ? (int)efc[i + 1] : 0;
        ACC(0, A0.x, T0.x)  ACC(2, A0.y, T0.y)  ACC(4, A0.z, T0.z)  ACC(6, A0.w, T0.w)
        ACC(8, A1.x, T1.x)  ACC(10, A1.y, T1.y) ACC(12, A1.z, T1.z) ACC(14, A1.w, T1.w)
        ACC(16, A2.x, Tc.x) ACC(18, A2.y, Tc.y)
    }
#undef ACC

    u32 sp[10];
#pragma unroll
    for (int jq = 0; jq < 5; jq++) {
        sp[2 * jq]     = (u32)f2bf(s[4 * jq + 0]) | ((u32)f2bf(s[4 * jq + 1]) << 16);
        sp[2 * jq + 1] = (u32)f2bf(s[4 * jq + 2]) | ((u32)f2bf(s[4 * jq + 3]) << 16);
    }
    *(uint4*)(tline + off16a)       = make_uint4(sp[0], sp[1], sp[2], sp[3]);
    *(uint4*)(tline + off16a + 128) = make_uint4(sp[4], sp[5], sp[6], sp[7]);
    *(uint2*)(tline + off8c)        = make_uint2(sp[8], sp[9]);
}

// ------- aggB: dense per-node MLP with SCALAR (SGPR) weights -------
// r14 diagnosis: ~440 ds_read_b128/thread made the old aggB LDS-issue/latency-bound
// (VALUBusy 25%, 139us). Now: half is per-wave uniform -> every weight access is a
// wave-uniform address -> s_load + v_fma(v,s,v). LDS only for the two cross-half
// reductions (m and o), ~18 DS ops/thread.

__global__ __launch_bounds__(256) void aggB_kernel(
        const u16* __restrict__ ts_x, const u16* __restrict__ ts_z,
        const float* __restrict__ h_to_x, const float* __restrict__ h_to_z,
        const float* __restrict__ logit_x, const float* __restrict__ logit_z,
        const float* __restrict__ Wm2_x, const float* __restrict__ Wm2_z,
        const float* __restrict__ We1_x, const float* __restrict__ We1_z,
        const float* __restrict__ We2_x, const float* __restrict__ We2_z,
        float* __restrict__ out) {
    int side = blockIdx.x >> 10;
    const u16* ts = side ? ts_z : ts_x;
    const float* __restrict__ h_to = side ? h_to_z : h_to_x;
    const float* __restrict__ logit = side ? logit_z : logit_x;
    const float* __restrict__ Wm2 = side ? Wm2_z : Wm2_x;
    const float* __restrict__ We1 = side ? We1_z : We1_x;
    const float* __restrict__ We2 = side ? We2_z : We2_x;

    __shared__ __attribute__((aligned(16))) float mbuf[2][32][4][20];  // 20,480 B
    __shared__ __attribute__((aligned(16))) float obuf[32][4][36];     // 18,432 B

    int tid = threadIdx.x;
    int half = tid >> 7;                                   // per-wave uniform
    int hoff = __builtin_amdgcn_readfirstlane(half * 20);  // SGPR
    int lane = tid & 63;
    int sub = (tid >> 6) & 1;
    int b = lane & 3;
    int cloc = sub * 16 + (lane >> 2);
    int c = (blockIdx.x & 1023) * 32 + cloc;
    int ch = half * 4 + b;

    // ---- read s slice (20 bf16, interleaved layout; ts holds s after aggA) ----
    float s[20];
    {
        const char* sv = (const char*)ts + (size_t)c * 320;
        uint4 S0 = *(const uint4*)(sv + ch * 16);
        uint4 S1 = *(const uint4*)(sv + 128 + ch * 16);
        uint2 S2 = *(const uint2*)(sv + 256 + ch * 8);
        s[0] = bflo(S0.x);  s[1] = bfhi(S0.x);  s[2] = bflo(S0.y);  s[3] = bfhi(S0.y);
        s[4] = bflo(S0.z);  s[5] = bfhi(S0.z);  s[6] = bflo(S0.w);  s[7] = bfhi(S0.w);
        s[8] = bflo(S1.x);  s[9] = bfhi(S1.x);  s[10] = bflo(S1.y); s[11] = bfhi(S1.y);
        s[12] = bflo(S1.z); s[13] = bfhi(S1.z); s[14] = bflo(S1.w); s[15] = bfhi(S1.w);
        s[16] = bflo(S2.x); s[17] = bfhi(S2.x); s[18] = bflo(S2.y); s[19] = bfhi(S2.y);
    }

    // ---- m partial: mm_p[k] = sum_j s[j] * Wm2[(hoff+j)*20 + k] (scalar weights) ----
    float4 m4[5];
#pragma unroll
    for (int kq = 0; kq < 5; kq++) m4[kq] = make_float4(0.f, 0.f, 0.f, 0.f);
    {
        const float* __restrict__ wm = Wm2 + hoff * MSGD;
#pragma unroll
        for (int j = 0; j < 20; j++) {
            float sj = s[j];
            const float* wr = wm + j * MSGD;
            SFMA4(m4[0], sj, wr) SFMA4(m4[1], sj, wr + 4) SFMA4(m4[2], sj, wr + 8)
            SFMA4(m4[3], sj, wr + 12) SFMA4(m4[4], sj, wr + 16)
        }
    }
    // cross-half combine via LDS
    {
        float4* mrow = (float4*)&mbuf[half][cloc][b][0];
        mrow[0] = m4[0]; mrow[1] = m4[1]; mrow[2] = m4[2]; mrow[3] = m4[3]; mrow[4] = m4[4];
    }
    __syncthreads();
    float mm[MSGD];
    {
        const float4* mo = (const float4*)&mbuf[half ^ 1][cloc][b][0];
#pragma unroll
        for (int kq = 0; kq < 5; kq++) {
            float4 o = mo[kq];
            mm[4 * kq + 0] = m4[kq].x + o.x; mm[4 * kq + 1] = m4[kq].y + o.y;
            mm[4 * kq + 2] = m4[kq].z + o.z; mm[4 * kq + 3] = m4[kq].w + o.w;
        }
    }

    // ---- a = relu(logit*We1l + X@We1b + mm@We1a) over this half's 20 comps ----
    float4 a0, a1, a2, a3, a4;
    {
        float lg = logit[(size_t)b * NCN + c];
        const float* wl = We1 + (MSGD + DIM) * HID + hoff;
        a0 = make_float4(lg * wl[0], lg * wl[1], lg * wl[2], lg * wl[3]);
        a1 = make_float4(lg * wl[4], lg * wl[5], lg * wl[6], lg * wl[7]);
        a2 = make_float4(lg * wl[8], lg * wl[9], lg * wl[10], lg * wl[11]);
        a3 = make_float4(lg * wl[12], lg * wl[13], lg * wl[14], lg * wl[15]);
        a4 = make_float4(lg * wl[16], lg * wl[17], lg * wl[18], lg * wl[19]);
        const float4* Xp = (const float4*)(h_to + ((size_t)b * NCN + c) * DIM);
#define PROW(xr, row) { const float* wr = We1 + (MSGD + (row)) * HID + hoff; \
        SFMA4(a0, (xr), wr) SFMA4(a1, (xr), wr + 4) SFMA4(a2, (xr), wr + 8) \
        SFMA4(a3, (xr), wr + 12) SFMA4(a4, (xr), wr + 16) }
#pragma unroll
        for (int q = 0; q < DIM / 4; q++) {
            float4 x = Xp[q];
            PROW(x.x, 4 * q + 0) PROW(x.y, 4 * q + 1)
            PROW(x.z, 4 * q + 2) PROW(x.w, 4 * q + 3)
        }
#undef PROW
#pragma unroll
        for (int k = 0; k < MSGD; k++) {
            float mk = mm[k];
            const float* wr = We1 + k * HID + hoff;
            SFMA4(a0, mk, wr) SFMA4(a1, mk, wr + 4) SFMA4(a2, mk, wr + 8)
            SFMA4(a3, mk, wr + 12) SFMA4(a4, mk, wr + 16)
        }
    }
    a0.x = fmaxf(a0.x, 0.f); a0.y = fmaxf(a0.y, 0.f); a0.z = fmaxf(a0.z, 0.f); a0.w = fmaxf(a0.w, 0.f);
    a1.x = fmaxf(a1.x, 0.f); a1.y = fmaxf(a1.y, 0.f); a1.z = fmaxf(a1.z, 0.f); a1.w = fmaxf(a1.w, 0.f);
    a2.x = fmaxf(a2.x, 0.f); a2.y = fmaxf(a2.y, 0.f); a2.z = fmaxf(a2.z, 0.f); a2.w = fmaxf(a2.w, 0.f);
    a3.x = fmaxf(a3.x, 0.f); a3.y = fmaxf(a3.y, 0.f); a3.z = fmaxf(a3.z, 0.f); a3.w = fmaxf(a3.w, 0.f);
    a4.x = fmaxf(a4.x, 0.f); a4.y = fmaxf(a4.y, 0.f); a4.z = fmaxf(a4.z, 0.f); a4.w = fmaxf(a4.w, 0.f);

    // ---- o partial: o[d] += a[h] * We2[(hoff+h)*32 + d] (scalar weights) ----
    float4 o4[8];
#pragma unroll
    for (int dq = 0; dq < 8; dq++) o4[dq] = make_float4(0.f, 0.f, 0.f, 0.f);
#define OROW(av, h) { const float* wr = We2 + (hoff + (h)) * DIM; \
    SFMA4(o4[0], (av), wr) SFMA4(o4[1], (av), wr + 4) SFMA4(o4[2], (av), wr + 8) \
    SFMA4(o4[3], (av), wr + 12) SFMA4(o4[4], (av), wr + 16) SFMA4(o4[5], (av), wr + 20) \
    SFMA4(o4[6], (av), wr + 24) SFMA4(o4[7], (av), wr + 28) }
    OROW(a0.x, 0)  OROW(a0.y, 1)  OROW(a0.z, 2)  OROW(a0.w, 3)
    OROW(a1.x, 4)  OROW(a1.y, 5)  OROW(a1.z, 6)  OROW(a1.w, 7)
    OROW(a2.x, 8)  OROW(a2.y, 9)  OROW(a2.z, 10) OROW(a2.w, 11)
    OROW(a3.x, 12) OROW(a3.y, 13) OROW(a3.z, 14) OROW(a3.w, 15)
    OROW(a4.x, 16) OROW(a4.y, 17) OROW(a4.z, 18) OROW(a4.w, 19)
#undef OROW

    // cross-half combine via LDS: half 1 deposits, half 0 adds + stores
    if (half) {
        float4* orow = (float4*)&obuf[cloc][b][0];
#pragma unroll
        for (int dq = 0; dq < 8; dq++) orow[dq] = o4[dq];
    }
    __syncthreads();
    if (!half) {
        const float4* orow = (const float4*)&obuf[cloc][b][0];
        float4* O = (float4*)(out + (size_t)side * (NB * NCN * DIM)
                                  + ((size_t)b * NCN + c) * DIM);
#pragma unroll
        for (int dq = 0; dq < 8; dq++) {
            float4 t = orow[dq];
            O[dq] = make_float4(o4[dq].x + t.x, o4[dq].y + t.y,
                                o4[dq].z + t.z, o4[dq].w + t.w);
        }
    }
}

// ---------------- host ----------------

extern "C" void kernel_launch(void* const* d_in, const int* in_sizes, int n_in,
                              void* d_out, int out_size, void* d_ws, size_t ws_size,
                              hipStream_t stream) {
    const float* h_from   = (const float*)d_in[0];
    const float* h_to_x   = (const float*)d_in[1];
    const float* h_to_z   = (const float*)d_in[2];
    const float* hx_logit = (const float*)d_in[3];
    const float* hz_logit = (const float*)d_in[4];
    const int*   from_x   = (const int*)d_in[5];
    const int*   to_x     = (const int*)d_in[6];
    const int*   from_z   = (const int*)d_in[7];
    const int*   to_z     = (const int*)d_in[8];
    const float* Wm1_x    = (const float*)d_in[9];
    const float* Wm2_x    = (const float*)d_in[10];
    const float* Wm1_z    = (const float*)d_in[11];
    const float* Wm2_z    = (const float*)d_in[12];
    const float* We1_x    = (const float*)d_in[13];
    const float* We2_x    = (const float*)d_in[14];
    const float* We1_z    = (const float*)d_in[15];
    const float* We2_z    = (const float*)d_in[16];

    // Workspace layout (bytes), end = 68,419,584 (<= proven 85,328,128 budget)
    char* ws = (char*)d_ws;
    u16* U2h_x = (u16*)(ws);                       // 65536*320 = 20,971,520
    u16* U2h_z = (u16*)(ws + 20971520);            // 20,971,520
    u16* ts_x  = (u16*)(ws + 41943040);            // 32768*320 = 10,485,760 (T, then s)
    u16* ts_z  = (u16*)(ws + 52428800);            // 10,485,760
    u16* ef_x  = (u16*)(ws + 62914560);            // 32768*40*2 = 2,621,440
    u16* ef_z  = (u16*)(ws + 65536000);            // 2,621,440
    int* cnt_x = (int*)(ws + 68157440);            // 131,072
    int* cnt_z = (int*)(ws + 68288512);            // 131,072
    float* out = (float*)d_out;

    hipMemsetAsync(ws + 68157440, 0, 262144, stream);  // zero cnt_x + cnt_z
    scatter_slot<<<2048, 256, 0, stream>>>(to_x, from_x, to_z, from_z,
                                           cnt_x, cnt_z, ef_x, ef_z);
    precompU_both<<<4096, 256, 0, stream>>>(h_from, Wm1_x, Wm1_z, U2h_x, U2h_z);
    precompT_both<<<2048, 256, 0, stream>>>(h_to_x, h_to_z, Wm1_x, Wm1_z, ts_x, ts_z);
    aggA_kernel<<<2048, 256, 0, stream>>>(U2h_x, U2h_z, ts_x, ts_z,
                                          cnt_x, cnt_z, ef_x, ef_z);
    aggB_kernel<<<2048, 256, 0, stream>>>(ts_x, ts_z, h_to_x, h_to_z,
                                          hx_logit, hz_logit,
                                          Wm2_x, Wm2_z, We1_x, We1_z,
                                          We2_x, We2_z, out);
}

// Round 16
// 165.748 us; speedup vs baseline: 2.3354x; 1.3175x over previous
//
#include <hip/hip_runtime.h>

// Problem constants (from reference)
#define NVN 65536
#define NCN 32768
#define NB 4
#define DIM 32
#define NE 262144
#define HID 40
#define MSGD 20
#define SLOT 40        // edge slots per check node (Poisson(8) max-deg ~25 << 40)

typedef unsigned short u16;
typedef unsigned int u32;
typedef __attribute__((ext_vector_type(8))) short bf16x8;
typedef __attribute__((ext_vector_type(4))) float f32x4;

// bf16 helpers (RNE pack, cheap unpack)
__device__ __forceinline__ u16 f2bf(float f) {
    u32 u = __float_as_uint(f);
    u += 0x7fff + ((u >> 16) & 1);
    return (u16)(u >> 16);
}
__device__ __forceinline__ float bflo(u32 u) { return __uint_as_float(u << 16); }
__device__ __forceinline__ float bfhi(u32 u) { return __uint_as_float(u & 0xffff0000u); }

#define SFMA4(acc, a, wp) { (acc).x += (a) * (wp)[0]; (acc).y += (a) * (wp)[1]; \
                            (acc).z += (a) * (wp)[2]; (acc).w += (a) * (wp)[3]; }

// ---------------- direct slot-scatter ----------------

__global__ __launch_bounds__(256) void scatter_slot(const int* __restrict__ to_x,
                                                    const int* __restrict__ from_x,
                                                    const int* __restrict__ to_z,
                                                    const int* __restrict__ from_z,
                                                    int* __restrict__ cnt_x,
                                                    int* __restrict__ cnt_z,
                                                    u16* __restrict__ ef_x,
                                                    u16* __restrict__ ef_z) {
    int bid = blockIdx.x;
    int e = (bid & 1023) * 256 + threadIdx.x;
    const int* t; const int* f; int* cnt; u16* ef;
    if (bid < 1024) { t = to_x; f = from_x; cnt = cnt_x; ef = ef_x; }
    else            { t = to_z; f = from_z; cnt = cnt_z; ef = ef_z; }
    int c = t[e];
    int pos = atomicAdd(&cnt[c], 1);
    if (pos < SLOT) ef[c * SLOT + pos] = (u16)f[e];
}

// ------- precompU: BOTH sides, scalar weights (wave-uniform hoff) -------

__global__ __launch_bounds__(256) void precompU_both(const float* __restrict__ h_from,
                                                     const float* __restrict__ Wm1_x,
                                                     const float* __restrict__ Wm1_z,
                                                     u16* __restrict__ U2h_x,
                                                     u16* __restrict__ U2h_z) {
    int side = blockIdx.x >> 11;
    const float* __restrict__ Wm1 = side ? Wm1_z : Wm1_x;
    u16* U2h = side ? U2h_z : U2h_x;

    int tid = threadIdx.x;
    int half = tid >> 7;
    int hoff = __builtin_amdgcn_readfirstlane(half * 20);
    int lane = tid & 63;
    int sub = (tid >> 6) & 1;
    int b = lane & 3;
    int vloc = sub * 16 + (lane >> 2);
    int v = (blockIdx.x & 2047) * 32 + vloc;
    int ch = half * 4 + b;

    const float4* hf4 = (const float4*)(h_from + ((size_t)b * NVN + v) * DIM);
    float4 acc4[5];
#pragma unroll
    for (int jq = 0; jq < 5; jq++) acc4[jq] = make_float4(0.f, 0.f, 0.f, 0.f);
#pragma unroll
    for (int q = 0; q < DIM / 4; q++) {
        float4 x = hf4[q];
#define WROW(xr, row) { const float* wr = Wm1 + (row) * HID + hoff; \
        SFMA4(acc4[0], (xr), wr) SFMA4(acc4[1], (xr), wr + 4) SFMA4(acc4[2], (xr), wr + 8) \
        SFMA4(acc4[3], (xr), wr + 12) SFMA4(acc4[4], (xr), wr + 16) }
        WROW(x.x, 4 * q + 0) WROW(x.y, 4 * q + 1) WROW(x.z, 4 * q + 2) WROW(x.w, 4 * q + 3)
#undef WROW
    }
    u32 p[10];
#pragma unroll
    for (int jq = 0; jq < 5; jq++) {
        p[2 * jq]     = (u32)f2bf(acc4[jq].x) | ((u32)f2bf(acc4[jq].y) << 16);
        p[2 * jq + 1] = (u32)f2bf(acc4[jq].z) | ((u32)f2bf(acc4[jq].w) << 16);
    }
    char* dst = (char*)U2h + (size_t)v * 320;
    *(uint4*)(dst + ch * 16)       = make_uint4(p[0], p[1], p[2], p[3]);
    *(uint4*)(dst + 128 + ch * 16) = make_uint4(p[4], p[5], p[6], p[7]);
    *(uint2*)(dst + 256 + ch * 8)  = make_uint2(p[8], p[9]);
}

// ------- precompT: BOTH sides, scalar weights (Wm1 rows 32..63) -------

__global__ __launch_bounds__(256) void precompT_both(
        const float* __restrict__ h_to_x, const float* __restrict__ h_to_z,
        const float* __restrict__ Wm1_x, const float* __restrict__ Wm1_z,
        u16* __restrict__ ts_x, u16* __restrict__ ts_z) {
    int side = blockIdx.x >> 10;
    const float* __restrict__ h_to = side ? h_to_z : h_to_x;
    const float* __restrict__ Wm1 = side ? Wm1_z : Wm1_x;
    u16* ts = side ? ts_z : ts_x;

    int tid = threadIdx.x;
    int half = tid >> 7;
    int hoff = __builtin_amdgcn_readfirstlane(half * 20);
    int lane = tid & 63;
    int sub = (tid >> 6) & 1;
    int b = lane & 3;
    int cloc = sub * 16 + (lane >> 2);
    int c = (blockIdx.x & 1023) * 32 + cloc;
    int ch = half * 4 + b;

    const float4* h4 = (const float4*)(h_to + ((size_t)b * NCN + c) * DIM);
    float4 acc4[5];
#pragma unroll
    for (int jq = 0; jq < 5; jq++) acc4[jq] = make_float4(0.f, 0.f, 0.f, 0.f);
#pragma unroll
    for (int q = 0; q < DIM / 4; q++) {
        float4 x = h4[q];
#define WROW(xr, row) { const float* wr = Wm1 + (DIM + (row)) * HID + hoff; \
        SFMA4(acc4[0], (xr), wr) SFMA4(acc4[1], (xr), wr + 4) SFMA4(acc4[2], (xr), wr + 8) \
        SFMA4(acc4[3], (xr), wr + 12) SFMA4(acc4[4], (xr), wr + 16) }
        WROW(x.x, 4 * q + 0) WROW(x.y, 4 * q + 1) WROW(x.z, 4 * q + 2) WROW(x.w, 4 * q + 3)
#undef WROW
    }
    u32 p[10];
#pragma unroll
    for (int jq = 0; jq < 5; jq++) {
        p[2 * jq]     = (u32)f2bf(acc4[jq].x) | ((u32)f2bf(acc4[jq].y) << 16);
        p[2 * jq + 1] = (u32)f2bf(acc4[jq].z) | ((u32)f2bf(acc4[jq].w) << 16);
    }
    char* dst = (char*)ts + (size_t)c * 320;
    *(uint4*)(dst + ch * 16)       = make_uint4(p[0], p[1], p[2], p[3]);
    *(uint4*)(dst + 128 + ch * 16) = make_uint4(p[4], p[5], p[6], p[7]);
    *(uint2*)(dst + 256 + ch * 8)  = make_uint2(p[8], p[9]);
}

// ------- prepW: per side, build padded bf16 weight mats for the MFMA GEMMs -------
// BW[96][48]: rows 0..39 = combo = Wm2 @ We1[0:20]; rows 40..71 = We1[20:52];
// row 72 = We1[52]; rest 0.  W2[64][32]: rows 0..39 = We2; rest 0.

__global__ __launch_bounds__(256) void prepW(
        const float* __restrict__ Wm2_x, const float* __restrict__ Wm2_z,
        const float* __restrict__ We1_x, const float* __restrict__ We1_z,
        const float* __restrict__ We2_x, const float* __restrict__ We2_z,
        u16* __restrict__ BW_x, u16* __restrict__ BW_z,
        u16* __restrict__ W2_x, u16* __restrict__ W2_z) {
    int side = blockIdx.x;
    const float* Wm2 = side ? Wm2_z : Wm2_x;
    const float* We1 = side ? We1_z : We1_x;
    const float* We2 = side ? We2_z : We2_x;
    u16* BW = side ? BW_z : BW_x;
    u16* W2 = side ? W2_z : W2_x;
    int tid = threadIdx.x;
    for (int i = tid; i < 96 * 48; i += 256) {
        int row = i / 48, col = i % 48;
        float v = 0.f;
        if (col < 40) {
            if (row < 40) {
                for (int k = 0; k < MSGD; k++) v += Wm2[row * MSGD + k] * We1[k * HID + col];
            } else if (row < 72) {
                v = We1[(MSGD + row - 40) * HID + col];
            } else if (row == 72) {
                v = We1[(MSGD + DIM) * HID + col];
            }
        }
        BW[i] = f2bf(v);
    }
    for (int i = tid; i < 64 * 32; i += 256) {
        int row = i / 32, col = i % 32;
        W2[i] = (row < 40) ? f2bf(We2[row * 32 + col]) : (u16)0;
    }
}

// ------- aggA: pure gather+relu-sum, BOTH sides. UNCHANGED (r14/r15, fast). -------

__global__ __launch_bounds__(256, 8) void aggA_kernel(
        const u16* __restrict__ U2h_x, const u16* __restrict__ U2h_z,
        u16* __restrict__ ts_x, u16* __restrict__ ts_z,
        const int* __restrict__ cnt_x, const int* __restrict__ cnt_z,
        const u16* __restrict__ ef_x, const u16* __restrict__ ef_z) {
    int side = blockIdx.x >> 10;
    const char* Ubase = (const char*)(side ? U2h_z : U2h_x);
    char* ts = (char*)(side ? ts_z : ts_x);
    const int* cnt = side ? cnt_z : cnt_x;
    const u16* ef = side ? ef_z : ef_x;

    int gt = (blockIdx.x & 1023) * 256 + threadIdx.x;
    int c = gt >> 3;
    int l8 = gt & 7;
    int off16a = l8 * 16;
    int off8c = 256 + l8 * 8;

    char* tline = ts + (size_t)c * 320;
    uint4 T0 = *(const uint4*)(tline + off16a);
    uint4 T1 = *(const uint4*)(tline + off16a + 128);
    uint2 Tc = *(const uint2*)(tline + off8c);

    float s[20];
#pragma unroll
    for (int k = 0; k < 20; k++) s[k] = 0.f;

    int cn = cnt[c];
    cn = (cn < SLOT) ? cn : SLOT;
    const u16* efc = ef + c * SLOT;

    int vA = (cn > 0) ? (int)efc[0] : 0;
#define ACC(su, aw, tw) { \
    s[su]     += fmaxf(bflo(aw) + bflo(tw), 0.f); \
    s[(su)+1] += fmaxf(bfhi(aw) + bfhi(tw), 0.f); }
    for (int i = 0; i < cn; ++i) {
        const char* pa = Ubase + (size_t)vA * 320;
        uint4 A0 = *(const uint4*)(pa + off16a);
        uint4 A1 = *(const uint4*)(pa + off16a + 128);
        uint2 A2 = *(const uint2*)(pa + off8c);
        vA = (i + 1 < cn) ? (int)efc[i + 1] : 0;
        ACC(0, A0.x, T0.x)  ACC(2, A0.y, T0.y)  ACC(4, A0.z, T0.z)  ACC(6, A0.w, T0.w)
        ACC(8, A1.x, T1.x)  ACC(10, A1.y, T1.y) ACC(12, A1.z, T1.z) ACC(14, A1.w, T1.w)
        ACC(16, A2.x, Tc.x) ACC(18, A2.y, Tc.y)
    }
#undef ACC

    u32 sp[10];
#pragma unroll
    for (int jq = 0; jq < 5; jq++) {
        sp[2 * jq]     = (u32)f2bf(s[4 * jq + 0]) | ((u32)f2bf(s[4 * jq + 1]) << 16);
        sp[2 * jq + 1] = (u32)f2bf(s[4 * jq + 2]) | ((u32)f2bf(s[4 * jq + 3]) << 16);
    }
    *(uint4*)(tline + off16a)       = make_uint4(sp[0], sp[1], sp[2], sp[3]);
    *(uint4*)(tline + off16a + 128) = make_uint4(sp[4], sp[5], sp[6], sp[7]);
    *(uint2*)(tline + off8c)        = make_uint2(sp[8], sp[9]);
}

// ------- aggB_mfma: H = relu([s|X|lg] @ BW) ; out = H @ We2  (two bf16 MFMA GEMMs) -------
// 128 rows/block (consecutive c, fixed side,b), 4 waves. A-rows staged in LDS [128][96]
// bf16 (s from ts lines, X/lg converted); H [128][64] bf16 (k-pad zeroed). MFMA
// 16x16x32: A lane holds i=lane&15, k=ks+8*(lane>>4)+r; B mirrored; C/D row=
// (lane>>4)*4+r, col=lane&15 (HW-verified m89). B pad rows AND A pad cols are zero.

__global__ __launch_bounds__(256) void aggB_mfma(
        const u16* __restrict__ ts_x, const u16* __restrict__ ts_z,
        const float* __restrict__ h_to_x, const float* __restrict__ h_to_z,
        const float* __restrict__ logit_x, const float* __restrict__ logit_z,
        const u16* __restrict__ BW_x, const u16* __restrict__ BW_z,
        const u16* __restrict__ W2_x, const u16* __restrict__ W2_z,
        float* __restrict__ out) {
    __shared__ __attribute__((aligned(16))) u16 sA[128 * 96];   // 24,576 B
    __shared__ __attribute__((aligned(16))) u16 sH[128 * 64];   // 16,384 B
    __shared__ __attribute__((aligned(16))) u16 sBW[96 * 48];   //  9,216 B
    __shared__ __attribute__((aligned(16))) u16 sW2[64 * 32];   //  4,096 B

    int bid = blockIdx.x;
    int side = bid >> 10;
    const u16* ts = side ? ts_z : ts_x;
    const float* h_to = side ? h_to_z : h_to_x;
    const float* logit = side ? logit_z : logit_x;
    const u16* BWg = side ? BW_z : BW_x;
    const u16* W2g = side ? W2_z : W2_x;

    int tid = threadIdx.x;
    int rho0 = (bid & 1023) * 128;   // within-side row base
    int b = rho0 >> 15;              // uniform over the block
    int c0 = rho0 & 32767;

    // stage weights
    for (int i = tid; i < (96 * 48) / 8; i += 256)
        ((uint4*)sBW)[i] = ((const uint4*)BWg)[i];
    if (tid < (64 * 32) / 8) ((uint4*)sW2)[tid] = ((const uint4*)W2g)[tid];

    // stage A rows: part0 = s (from ts line chunks), part1 = X(bf16) + lg + zero pad
    {
        int r = tid >> 1;
        int part = tid & 1;
        int c = c0 + r;
        char* srow = (char*)sA + r * 192;
        if (part == 0) {
            const char* tr = (const char*)ts + (size_t)c * 320;
            uint4 p0 = *(const uint4*)(tr + b * 16);
            uint4 p1 = *(const uint4*)(tr + 128 + b * 16);
            uint2 p2 = *(const uint2*)(tr + 256 + b * 8);
            uint4 p3 = *(const uint4*)(tr + (4 + b) * 16);
            uint4 p4 = *(const uint4*)(tr + 128 + (4 + b) * 16);
            uint2 p5 = *(const uint2*)(tr + 256 + (4 + b) * 8);
            *(uint4*)(srow + 0)  = p0;
            *(uint4*)(srow + 16) = p1;
            *(uint2*)(srow + 32) = p2;
            *(uint2*)(srow + 40) = make_uint2(p3.x, p3.y);
            *(uint2*)(srow + 48) = make_uint2(p3.z, p3.w);
            *(uint2*)(srow + 56) = make_uint2(p4.x, p4.y);
            *(uint2*)(srow + 64) = make_uint2(p4.z, p4.w);
            *(uint2*)(srow + 72) = p5;
            char* hrow = (char*)sH + r * 128;   // H k-pad cols 48..63 -> 0
            *(uint4*)(hrow + 96)  = make_uint4(0, 0, 0, 0);
            *(uint4*)(hrow + 112) = make_uint4(0, 0, 0, 0);
        } else {
            const float4* xp = (const float4*)(h_to + ((size_t)b * NCN + c) * DIM);
#pragma unroll
            for (int q = 0; q < 4; q++) {
                float4 x0 = xp[2 * q], x1 = xp[2 * q + 1];
                u32 w0 = (u32)f2bf(x0.x) | ((u32)f2bf(x0.y) << 16);
                u32 w1 = (u32)f2bf(x0.z) | ((u32)f2bf(x0.w) << 16);
                u32 w2 = (u32)f2bf(x1.x) | ((u32)f2bf(x1.y) << 16);
                u32 w3 = (u32)f2bf(x1.z) | ((u32)f2bf(x1.w) << 16);
                *(uint4*)(srow + 80 + q * 16) = make_uint4(w0, w1, w2, w3);
            }
            float lg = logit[(size_t)b * NCN + c];
            *(uint4*)(srow + 144) = make_uint4((u32)f2bf(lg), 0, 0, 0);
            *(uint4*)(srow + 160) = make_uint4(0, 0, 0, 0);
            *(uint4*)(srow + 176) = make_uint4(0, 0, 0, 0);
        }
    }
    __syncthreads();

    int wid = tid >> 6;
    int lane = tid & 63;
    int li = lane & 15;
    int lk = lane >> 4;      // 0..3
    int rowq = lk * 4;       // C/D row group base

    // GEMM_A B-frags (3 col-tiles x 3 k-steps)
    bf16x8 bA[3][3];
#pragma unroll
    for (int jt = 0; jt < 3; jt++)
#pragma unroll
        for (int ks = 0; ks < 3; ks++) {
            bf16x8 v;
#pragma unroll
            for (int rr = 0; rr < 8; rr++)
                v[rr] = (short)sBW[(ks * 32 + lk * 8 + rr) * 48 + jt * 16 + li];
            bA[jt][ks] = v;
        }

#pragma unroll
    for (int rt = 0; rt < 2; rt++) {
        int rowloc = wid * 32 + rt * 16;
        const char* abase = (const char*)sA + (rowloc + li) * 192 + lk * 16;
        bf16x8 a0 = *(const bf16x8*)(abase);
        bf16x8 a1 = *(const bf16x8*)(abase + 64);
        bf16x8 a2 = *(const bf16x8*)(abase + 128);
#pragma unroll
        for (int jt = 0; jt < 3; jt++) {
            f32x4 acc = {0.f, 0.f, 0.f, 0.f};
            acc = __builtin_amdgcn_mfma_f32_16x16x32_bf16(a0, bA[jt][0], acc, 0, 0, 0);
            acc = __builtin_amdgcn_mfma_f32_16x16x32_bf16(a1, bA[jt][1], acc, 0, 0, 0);
            acc = __builtin_amdgcn_mfma_f32_16x16x32_bf16(a2, bA[jt][2], acc, 0, 0, 0);
#pragma unroll
            for (int rr = 0; rr < 4; rr++)
                sH[(rowloc + rowq + rr) * 64 + jt * 16 + li] = f2bf(fmaxf(acc[rr], 0.f));
        }
    }
    __syncthreads();

    // GEMM_B B-frags (2 col-tiles x 2 k-steps)
    bf16x8 bB[2][2];
#pragma unroll
    for (int jt = 0; jt < 2; jt++)
#pragma unroll
        for (int ks = 0; ks < 2; ks++) {
            bf16x8 v;
#pragma unroll
            for (int rr = 0; rr < 8; rr++)
                v[rr] = (short)sW2[(ks * 32 + lk * 8 + rr) * 32 + jt * 16 + li];
            bB[jt][ks] = v;
        }

    size_t rowg0 = (size_t)bid * 128;
#pragma unroll
    for (int rt = 0; rt < 2; rt++) {
        int rowloc = wid * 32 + rt * 16;
        const char* hbase = (const char*)sH + (rowloc + li) * 128 + lk * 16;
        bf16x8 h0 = *(const bf16x8*)(hbase);
        bf16x8 h1 = *(const bf16x8*)(hbase + 64);
#pragma unroll
        for (int jt = 0; jt < 2; jt++) {
            f32x4 acc = {0.f, 0.f, 0.f, 0.f};
            acc = __builtin_amdgcn_mfma_f32_16x16x32_bf16(h0, bB[jt][0], acc, 0, 0, 0);
            acc = __builtin_amdgcn_mfma_f32_16x16x32_bf16(h1, bB[jt][1], acc, 0, 0, 0);
#pragma unroll
            for (int rr = 0; rr < 4; rr++)
                out[(rowg0 + rowloc + rowq + rr) * 32 + jt * 16 + li] = acc[rr];
        }
    }
}

// ---------------- host ----------------

extern "C" void kernel_launch(void* const* d_in, const int* in_sizes, int n_in,
                              void* d_out, int out_size, void* d_ws, size_t ws_size,
                              hipStream_t stream) {
    const float* h_from   = (const float*)d_in[0];
    const float* h_to_x   = (const float*)d_in[1];
    const float* h_to_z   = (const float*)d_in[2];
    const float* hx_logit = (const float*)d_in[3];
    const float* hz_logit = (const float*)d_in[4];
    const int*   from_x   = (const int*)d_in[5];
    const int*   to_x     = (const int*)d_in[6];
    const int*   from_z   = (const int*)d_in[7];
    const int*   to_z     = (const int*)d_in[8];
    const float* Wm1_x    = (const float*)d_in[9];
    const float* Wm2_x    = (const float*)d_in[10];
    const float* Wm1_z    = (const float*)d_in[11];
    const float* Wm2_z    = (const float*)d_in[12];
    const float* We1_x    = (const float*)d_in[13];
    const float* We2_x    = (const float*)d_in[14];
    const float* We1_z    = (const float*)d_in[15];
    const float* We2_z    = (const float*)d_in[16];

    // Workspace layout (bytes), end = 68,446,208 (<= proven 85,328,128 budget)
    char* ws = (char*)d_ws;
    u16* U2h_x = (u16*)(ws);                       // 65536*320 = 20,971,520
    u16* U2h_z = (u16*)(ws + 20971520);            // 20,971,520
    u16* ts_x  = (u16*)(ws + 41943040);            // 32768*320 = 10,485,760 (T, then s)
    u16* ts_z  = (u16*)(ws + 52428800);            // 10,485,760
    u16* ef_x  = (u16*)(ws + 62914560);            // 32768*40*2 = 2,621,440
    u16* ef_z  = (u16*)(ws + 65536000);            // 2,621,440
    int* cnt_x = (int*)(ws + 68157440);            // 131,072
    int* cnt_z = (int*)(ws + 68288512);            // 131,072
    u16* BW_x  = (u16*)(ws + 68419584);            // 96*48*2 = 9,216
    u16* BW_z  = (u16*)(ws + 68428800);            // 9,216
    u16* W2_x  = (u16*)(ws + 68438016);            // 64*32*2 = 4,096
    u16* W2_z  = (u16*)(ws + 68442112);            // 4,096
    float* out = (float*)d_out;

    hipMemsetAsync(ws + 68157440, 0, 262144, stream);  // zero cnt_x + cnt_z
    scatter_slot<<<2048, 256, 0, stream>>>(to_x, from_x, to_z, from_z,
                                           cnt_x, cnt_z, ef_x, ef_z);
    precompU_both<<<4096, 256, 0, stream>>>(h_from, Wm1_x, Wm1_z, U2h_x, U2h_z);
    precompT_both<<<2048, 256, 0, stream>>>(h_to_x, h_to_z, Wm1_x, Wm1_z, ts_x, ts_z);
    prepW<<<2, 256, 0, stream>>>(Wm2_x, Wm2_z, We1_x, We1_z, We2_x, We2_z,
                                 BW_x, BW_z, W2_x, W2_z);
    aggA_kernel<<<2048, 256, 0, stream>>>(U2h_x, U2h_z, ts_x, ts_z,
                                          cnt_x, cnt_z, ef_x, ef_z);
    aggB_mfma<<<2048, 256, 0, stream>>>(ts_x, ts_z, h_to_x, h_to_z,
                                        hx_logit, hz_logit,
                                        BW_x, BW_z, W2_x, W2_z, out);
}

// Round 17
// 160.901 us; speedup vs baseline: 2.4058x; 1.0301x over previous
//
#include <hip/hip_runtime.h>

// Problem constants (from reference)
#define NVN 65536
#define NCN 32768
#define NB 4
#define DIM 32
#define NE 262144
#define HID 40
#define MSGD 20
#define SLOT 40        // edge slots per check node (Poisson(8) max-deg ~25 << 40)

typedef unsigned short u16;
typedef unsigned int u32;
typedef __attribute__((ext_vector_type(8))) short bf16x8;
typedef __attribute__((ext_vector_type(4))) float f32x4;

// bf16 helpers (RNE pack, cheap unpack)
__device__ __forceinline__ u16 f2bf(float f) {
    u32 u = __float_as_uint(f);
    u += 0x7fff + ((u >> 16) & 1);
    return (u16)(u >> 16);
}
__device__ __forceinline__ float bflo(u32 u) { return __uint_as_float(u << 16); }
__device__ __forceinline__ float bfhi(u32 u) { return __uint_as_float(u & 0xffff0000u); }
__device__ __forceinline__ u32 pk2(float a, float b) {
    return (u32)f2bf(a) | ((u32)f2bf(b) << 16);
}

// ---------------- direct slot-scatter ----------------

__global__ __launch_bounds__(256) void scatter_slot(const int* __restrict__ to_x,
                                                    const int* __restrict__ from_x,
                                                    const int* __restrict__ to_z,
                                                    const int* __restrict__ from_z,
                                                    int* __restrict__ cnt_x,
                                                    int* __restrict__ cnt_z,
                                                    u16* __restrict__ ef_x,
                                                    u16* __restrict__ ef_z) {
    int bid = blockIdx.x;
    int e = (bid & 1023) * 256 + threadIdx.x;
    const int* t; const int* f; int* cnt; u16* ef;
    if (bid < 1024) { t = to_x; f = from_x; cnt = cnt_x; ef = ef_x; }
    else            { t = to_z; f = from_z; cnt = cnt_z; ef = ef_z; }
    int c = t[e];
    int pos = atomicAdd(&cnt[c], 1);
    if (pos < SLOT) ef[c * SLOT + pos] = (u16)f[e];
}

// ------- precomp_mfma: D[row][0:40] = h[b][row][0:32] @ W[32][40], bf16 MFMA -------
// Generic over U (h=h_from, W=Wm1[0:32], nrows=NVN) and T (h=h_to, W=Wm1[32:64],
// nrows=NCN). One K=32 MFMA step per 16x16 tile; 128 rows/block, fixed (side,b).
// Output written as the interleaved 320B lines aggA consumes: chunk ch=p*4+b gets
// cols p*20..p*20+19 at {ch*16, 128+ch*16, 256+ch*8}.
// r16 lesson: VALU GEMV w/ streamed (SGPR or LDS) weights stalls at ~4-10x floor;
// matmul-shaped phases go to MFMA (old precompU: 55us, VALUBusy 31%, HBM 8%).

__global__ __launch_bounds__(256) void precomp_mfma(
        const float* __restrict__ h_x, const float* __restrict__ h_z,
        const float* __restrict__ W_x, const float* __restrict__ W_z,
        u16* __restrict__ dst_x, u16* __restrict__ dst_z,
        int nrows) {
    __shared__ __attribute__((aligned(16))) u16 sA[128 * 32];   //  8 KB
    __shared__ __attribute__((aligned(16))) u16 sB[32 * 48];    //  3 KB
    __shared__ __attribute__((aligned(16))) u16 sOut[128 * 40]; // 10 KB

    int bpb = nrows >> 7;            // blocks per (side,b)
    int bid = blockIdx.x;
    int side = bid / (bpb * 4);
    int rem = bid - side * (bpb * 4);
    int b = rem / bpb;
    int v0 = (rem - b * bpb) << 7;

    const float* __restrict__ h = side ? h_z : h_x;
    const float* __restrict__ W = side ? W_z : W_x;
    u16* dst = side ? dst_z : dst_x;

    int tid = threadIdx.x;

    // stage B: [32][48] bf16, cols 40..47 zero
    for (int i = tid; i < 32 * 48; i += 256) {
        int row = i / 48, col = i - row * 48;
        sB[i] = (col < 40) ? f2bf(W[row * 40 + col]) : (u16)0;
    }
    // stage A: 128 rows x 32 bf16 (each thread converts 16 floats)
    {
        int r = tid >> 1, p = tid & 1;
        const float4* hp = (const float4*)(h + ((size_t)b * nrows + v0 + r) * DIM + p * 16);
        float4 x0 = hp[0], x1 = hp[1], x2 = hp[2], x3 = hp[3];
        uint4* d = (uint4*)(sA + r * 32 + p * 16);
        d[0] = make_uint4(pk2(x0.x, x0.y), pk2(x0.z, x0.w), pk2(x1.x, x1.y), pk2(x1.z, x1.w));
        d[1] = make_uint4(pk2(x2.x, x2.y), pk2(x2.z, x2.w), pk2(x3.x, x3.y), pk2(x3.z, x3.w));
    }
    __syncthreads();

    int wid = tid >> 6;
    int lane = tid & 63;
    int li = lane & 15;
    int lk = lane >> 4;

    // B frags: 3 col-tiles, single K=32 step
    bf16x8 bfr[3];
#pragma unroll
    for (int jt = 0; jt < 3; jt++) {
        bf16x8 v;
#pragma unroll
        for (int rr = 0; rr < 8; rr++)
            v[rr] = (short)sB[(lk * 8 + rr) * 48 + jt * 16 + li];
        bfr[jt] = v;
    }

#pragma unroll
    for (int rt = 0; rt < 2; rt++) {
        int rowloc = wid * 32 + rt * 16;
        bf16x8 a = *(const bf16x8*)(sA + (rowloc + li) * 32 + lk * 8);
#pragma unroll
        for (int jt = 0; jt < 3; jt++) {
            f32x4 acc = {0.f, 0.f, 0.f, 0.f};
            acc = __builtin_amdgcn_mfma_f32_16x16x32_bf16(a, bfr[jt], acc, 0, 0, 0);
            int col = jt * 16 + li;
            if (col < 40) {
#pragma unroll
                for (int rr = 0; rr < 4; rr++)
                    sOut[(rowloc + lk * 4 + rr) * 40 + col] = f2bf(acc[rr]);
            }
        }
    }
    __syncthreads();

    // pack out: thread (r,p) writes chunk ch=p*4+b of row v0+r (3 pieces)
    {
        int r = tid >> 1, p = tid & 1;
        const u32* row = (const u32*)(sOut + r * 40);
        u32 w0 = row[p * 10 + 0], w1 = row[p * 10 + 1], w2 = row[p * 10 + 2];
        u32 w3 = row[p * 10 + 3], w4 = row[p * 10 + 4], w5 = row[p * 10 + 5];
        u32 w6 = row[p * 10 + 6], w7 = row[p * 10 + 7], w8 = row[p * 10 + 8];
        u32 w9 = row[p * 10 + 9];
        int ch = p * 4 + b;
        char* dl = (char*)dst + (size_t)(v0 + r) * 320;
        *(uint4*)(dl + ch * 16)       = make_uint4(w0, w1, w2, w3);
        *(uint4*)(dl + 128 + ch * 16) = make_uint4(w4, w5, w6, w7);
        *(uint2*)(dl + 256 + ch * 8)  = make_uint2(w8, w9);
    }
}

// ------- prepW: per side, build padded bf16 weight mats for the MFMA GEMMs -------

__global__ __launch_bounds__(256) void prepW(
        const float* __restrict__ Wm2_x, const float* __restrict__ Wm2_z,
        const float* __restrict__ We1_x, const float* __restrict__ We1_z,
        const float* __restrict__ We2_x, const float* __restrict__ We2_z,
        u16* __restrict__ BW_x, u16* __restrict__ BW_z,
        u16* __restrict__ W2_x, u16* __restrict__ W2_z) {
    int side = blockIdx.x;
    const float* Wm2 = side ? Wm2_z : Wm2_x;
    const float* We1 = side ? We1_z : We1_x;
    const float* We2 = side ? We2_z : We2_x;
    u16* BW = side ? BW_z : BW_x;
    u16* W2 = side ? W2_z : W2_x;
    int tid = threadIdx.x;
    for (int i = tid; i < 96 * 48; i += 256) {
        int row = i / 48, col = i % 48;
        float v = 0.f;
        if (col < 40) {
            if (row < 40) {
                for (int k = 0; k < MSGD; k++) v += Wm2[row * MSGD + k] * We1[k * HID + col];
            } else if (row < 72) {
                v = We1[(MSGD + row - 40) * HID + col];
            } else if (row == 72) {
                v = We1[(MSGD + DIM) * HID + col];
            }
        }
        BW[i] = f2bf(v);
    }
    for (int i = tid; i < 64 * 32; i += 256) {
        int row = i / 32, col = i % 32;
        W2[i] = (row < 40) ? f2bf(We2[row * 32 + col]) : (u16)0;
    }
}

// ------- aggA: pure gather+relu-sum, BOTH sides. UNCHANGED (r14/r15, fast). -------

__global__ __launch_bounds__(256, 8) void aggA_kernel(
        const u16* __restrict__ U2h_x, const u16* __restrict__ U2h_z,
        u16* __restrict__ ts_x, u16* __restrict__ ts_z,
        const int* __restrict__ cnt_x, const int* __restrict__ cnt_z,
        const u16* __restrict__ ef_x, const u16* __restrict__ ef_z) {
    int side = blockIdx.x >> 10;
    const char* Ubase = (const char*)(side ? U2h_z : U2h_x);
    char* ts = (char*)(side ? ts_z : ts_x);
    const int* cnt = side ? cnt_z : cnt_x;
    const u16* ef = side ? ef_z : ef_x;

    int gt = (blockIdx.x & 1023) * 256 + threadIdx.x;
    int c = gt >> 3;
    int l8 = gt & 7;
    int off16a = l8 * 16;
    int off8c = 256 + l8 * 8;

    char* tline = ts + (size_t)c * 320;
    uint4 T0 = *(const uint4*)(tline + off16a);
    uint4 T1 = *(const uint4*)(tline + off16a + 128);
    uint2 Tc = *(const uint2*)(tline + off8c);

    float s[20];
#pragma unroll
    for (int k = 0; k < 20; k++) s[k] = 0.f;

    int cn = cnt[c];
    cn = (cn < SLOT) ? cn : SLOT;
    const u16* efc = ef + c * SLOT;

    int vA = (cn > 0) ? (int)efc[0] : 0;
#define ACC(su, aw, tw) { \
    s[su]     += fmaxf(bflo(aw) + bflo(tw), 0.f); \
    s[(su)+1] += fmaxf(bfhi(aw) + bfhi(tw), 0.f); }
    for (int i = 0; i < cn; ++i) {
        const char* pa = Ubase + (size_t)vA * 320;
        uint4 A0 = *(const uint4*)(pa + off16a);
        uint4 A1 = *(const uint4*)(pa + off16a + 128);
        uint2 A2 = *(const uint2*)(pa + off8c);
        vA = (i + 1 < cn) ? (int)efc[i + 1] : 0;
        ACC(0, A0.x, T0.x)  ACC(2, A0.y, T0.y)  ACC(4, A0.z, T0.z)  ACC(6, A0.w, T0.w)
        ACC(8, A1.x, T1.x)  ACC(10, A1.y, T1.y) ACC(12, A1.z, T1.z) ACC(14, A1.w, T1.w)
        ACC(16, A2.x, Tc.x) ACC(18, A2.y, Tc.y)
    }
#undef ACC

    u32 sp[10];
#pragma unroll
    for (int jq = 0; jq < 5; jq++) {
        sp[2 * jq]     = pk2(s[4 * jq + 0], s[4 * jq + 1]);
        sp[2 * jq + 1] = pk2(s[4 * jq + 2], s[4 * jq + 3]);
    }
    *(uint4*)(tline + off16a)       = make_uint4(sp[0], sp[1], sp[2], sp[3]);
    *(uint4*)(tline + off16a + 128) = make_uint4(sp[4], sp[5], sp[6], sp[7]);
    *(uint2*)(tline + off8c)        = make_uint2(sp[8], sp[9]);
}

// ------- aggB_mfma: H = relu([s|X|lg] @ BW) ; out = H @ We2  (UNCHANGED, r16) -------

__global__ __launch_bounds__(256) void aggB_mfma(
        const u16* __restrict__ ts_x, const u16* __restrict__ ts_z,
        const float* __restrict__ h_to_x, const float* __restrict__ h_to_z,
        const float* __restrict__ logit_x, const float* __restrict__ logit_z,
        const u16* __restrict__ BW_x, const u16* __restrict__ BW_z,
        const u16* __restrict__ W2_x, const u16* __restrict__ W2_z,
        float* __restrict__ out) {
    __shared__ __attribute__((aligned(16))) u16 sA[128 * 96];   // 24,576 B
    __shared__ __attribute__((aligned(16))) u16 sH[128 * 64];   // 16,384 B
    __shared__ __attribute__((aligned(16))) u16 sBW[96 * 48];   //  9,216 B
    __shared__ __attribute__((aligned(16))) u16 sW2[64 * 32];   //  4,096 B

    int bid = blockIdx.x;
    int side = bid >> 10;
    const u16* ts = side ? ts_z : ts_x;
    const float* h_to = side ? h_to_z : h_to_x;
    const float* logit = side ? logit_z : logit_x;
    const u16* BWg = side ? BW_z : BW_x;
    const u16* W2g = side ? W2_z : W2_x;

    int tid = threadIdx.x;
    int rho0 = (bid & 1023) * 128;   // within-side row base
    int b = rho0 >> 15;              // uniform over the block
    int c0 = rho0 & 32767;

    for (int i = tid; i < (96 * 48) / 8; i += 256)
        ((uint4*)sBW)[i] = ((const uint4*)BWg)[i];
    if (tid < (64 * 32) / 8) ((uint4*)sW2)[tid] = ((const uint4*)W2g)[tid];

    {
        int r = tid >> 1;
        int part = tid & 1;
        int c = c0 + r;
        char* srow = (char*)sA + r * 192;
        if (part == 0) {
            const char* tr = (const char*)ts + (size_t)c * 320;
            uint4 p0 = *(const uint4*)(tr + b * 16);
            uint4 p1 = *(const uint4*)(tr + 128 + b * 16);
            uint2 p2 = *(const uint2*)(tr + 256 + b * 8);
            uint4 p3 = *(const uint4*)(tr + (4 + b) * 16);
            uint4 p4 = *(const uint4*)(tr + 128 + (4 + b) * 16);
            uint2 p5 = *(const uint2*)(tr + 256 + (4 + b) * 8);
            *(uint4*)(srow + 0)  = p0;
            *(uint4*)(srow + 16) = p1;
            *(uint2*)(srow + 32) = p2;
            *(uint2*)(srow + 40) = make_uint2(p3.x, p3.y);
            *(uint2*)(srow + 48) = make_uint2(p3.z, p3.w);
            *(uint2*)(srow + 56) = make_uint2(p4.x, p4.y);
            *(uint2*)(srow + 64) = make_uint2(p4.z, p4.w);
            *(uint2*)(srow + 72) = p5;
            char* hrow = (char*)sH + r * 128;
            *(uint4*)(hrow + 96)  = make_uint4(0, 0, 0, 0);
            *(uint4*)(hrow + 112) = make_uint4(0, 0, 0, 0);
        } else {
            const float4* xp = (const float4*)(h_to + ((size_t)b * NCN + c) * DIM);
#pragma unroll
            for (int q = 0; q < 4; q++) {
                float4 x0 = xp[2 * q], x1 = xp[2 * q + 1];
                *(uint4*)(srow + 80 + q * 16) =
                    make_uint4(pk2(x0.x, x0.y), pk2(x0.z, x0.w),
                               pk2(x1.x, x1.y), pk2(x1.z, x1.w));
            }
            float lg = logit[(size_t)b * NCN + c];
            *(uint4*)(srow + 144) = make_uint4((u32)f2bf(lg), 0, 0, 0);
            *(uint4*)(srow + 160) = make_uint4(0, 0, 0, 0);
            *(uint4*)(srow + 176) = make_uint4(0, 0, 0, 0);
        }
    }
    __syncthreads();

    int wid = tid >> 6;
    int lane = tid & 63;
    int li = lane & 15;
    int lk = lane >> 4;
    int rowq = lk * 4;

    bf16x8 bA[3][3];
#pragma unroll
    for (int jt = 0; jt < 3; jt++)
#pragma unroll
        for (int ks = 0; ks < 3; ks++) {
            bf16x8 v;
#pragma unroll
            for (int rr = 0; rr < 8; rr++)
                v[rr] = (short)sBW[(ks * 32 + lk * 8 + rr) * 48 + jt * 16 + li];
            bA[jt][ks] = v;
        }

#pragma unroll
    for (int rt = 0; rt < 2; rt++) {
        int rowloc = wid * 32 + rt * 16;
        const char* abase = (const char*)sA + (rowloc + li) * 192 + lk * 16;
        bf16x8 a0 = *(const bf16x8*)(abase);
        bf16x8 a1 = *(const bf16x8*)(abase + 64);
        bf16x8 a2 = *(const bf16x8*)(abase + 128);
#pragma unroll
        for (int jt = 0; jt < 3; jt++) {
            f32x4 acc = {0.f, 0.f, 0.f, 0.f};
            acc = __builtin_amdgcn_mfma_f32_16x16x32_bf16(a0, bA[jt][0], acc, 0, 0, 0);
            acc = __builtin_amdgcn_mfma_f32_16x16x32_bf16(a1, bA[jt][1], acc, 0, 0, 0);
            acc = __builtin_amdgcn_mfma_f32_16x16x32_bf16(a2, bA[jt][2], acc, 0, 0, 0);
#pragma unroll
            for (int rr = 0; rr < 4; rr++)
                sH[(rowloc + rowq + rr) * 64 + jt * 16 + li] = f2bf(fmaxf(acc[rr], 0.f));
        }
    }
    __syncthreads();

    bf16x8 bB[2][2];
#pragma unroll
    for (int jt = 0; jt < 2; jt++)
#pragma unroll
        for (int ks = 0; ks < 2; ks++) {
            bf16x8 v;
#pragma unroll
            for (int rr = 0; rr < 8; rr++)
                v[rr] = (short)sW2[(ks * 32 + lk * 8 + rr) * 32 + jt * 16 + li];
            bB[jt][ks] = v;
        }

    size_t rowg0 = (size_t)bid * 128;
#pragma unroll
    for (int rt = 0; rt < 2; rt++) {
        int rowloc = wid * 32 + rt * 16;
        const char* hbase = (const char*)sH + (rowloc + li) * 128 + lk * 16;
        bf16x8 h0 = *(const bf16x8*)(hbase);
        bf16x8 h1 = *(const bf16x8*)(hbase + 64);
#pragma unroll
        for (int jt = 0; jt < 2; jt++) {
            f32x4 acc = {0.f, 0.f, 0.f, 0.f};
            acc = __builtin_amdgcn_mfma_f32_16x16x32_bf16(h0, bB[jt][0], acc, 0, 0, 0);
            acc = __builtin_amdgcn_mfma_f32_16x16x32_bf16(h1, bB[jt][1], acc, 0, 0, 0);
#pragma unroll
            for (int rr = 0; rr < 4; rr++)
                out[(rowg0 + rowloc + rowq + rr) * 32 + jt * 16 + li] = acc[rr];
        }
    }
}

// ---------------- host ----------------

extern "C" void kernel_launch(void* const* d_in, const int* in_sizes, int n_in,
                              void* d_out, int out_size, void* d_ws, size_t ws_size,
                              hipStream_t stream) {
    const float* h_from   = (const float*)d_in[0];
    const float* h_to_x   = (const float*)d_in[1];
    const float* h_to_z   = (const float*)d_in[2];
    const float* hx_logit = (const float*)d_in[3];
    const float* hz_logit = (const float*)d_in[4];
    const int*   from_x   = (const int*)d_in[5];
    const int*   to_x     = (const int*)d_in[6];
    const int*   from_z   = (const int*)d_in[7];
    const int*   to_z     = (const int*)d_in[8];
    const float* Wm1_x    = (const float*)d_in[9];
    const float* Wm2_x    = (const float*)d_in[10];
    const float* Wm1_z    = (const float*)d_in[11];
    const float* Wm2_z    = (const float*)d_in[12];
    const float* We1_x    = (const float*)d_in[13];
    const float* We2_x    = (const float*)d_in[14];
    const float* We1_z    = (const float*)d_in[15];
    const float* We2_z    = (const float*)d_in[16];

    // Workspace layout (bytes), end = 68,446,208 (<= proven 85,328,128 budget)
    char* ws = (char*)d_ws;
    u16* U2h_x = (u16*)(ws);                       // 65536*320 = 20,971,520
    u16* U2h_z = (u16*)(ws + 20971520);            // 20,971,520
    u16* ts_x  = (u16*)(ws + 41943040);            // 32768*320 = 10,485,760 (T, then s)
    u16* ts_z  = (u16*)(ws + 52428800);            // 10,485,760
    u16* ef_x  = (u16*)(ws + 62914560);            // 32768*40*2 = 2,621,440
    u16* ef_z  = (u16*)(ws + 65536000);            // 2,621,440
    int* cnt_x = (int*)(ws + 68157440);            // 131,072
    int* cnt_z = (int*)(ws + 68288512);            // 131,072
    u16* BW_x  = (u16*)(ws + 68419584);            // 96*48*2 = 9,216
    u16* BW_z  = (u16*)(ws + 68428800);            // 9,216
    u16* W2_x  = (u16*)(ws + 68438016);            // 64*32*2 = 4,096
    u16* W2_z  = (u16*)(ws + 68442112);            // 4,096
    float* out = (float*)d_out;

    hipMemsetAsync(ws + 68157440, 0, 262144, stream);  // zero cnt_x + cnt_z
    scatter_slot<<<2048, 256, 0, stream>>>(to_x, from_x, to_z, from_z,
                                           cnt_x, cnt_z, ef_x, ef_z);
    // U = h_from @ Wm1[0:32]  (both sides read the same h_from)
    precomp_mfma<<<4096, 256, 0, stream>>>(h_from, h_from, Wm1_x, Wm1_z,
                                           U2h_x, U2h_z, NVN);
    // T = h_to @ Wm1[32:64]
    precomp_mfma<<<2048, 256, 0, stream>>>(h_to_x, h_to_z,
                                           Wm1_x + DIM * HID, Wm1_z + DIM * HID,
                                           ts_x, ts_z, NCN);
    prepW<<<2, 256, 0, stream>>>(Wm2_x, Wm2_z, We1_x, We1_z, We2_x, We2_z,
                                 BW_x, BW_z, W2_x, W2_z);
    aggA_kernel<<<2048, 256, 0, stream>>>(U2h_x, U2h_z, ts_x, ts_z,
                                          cnt_x, cnt_z, ef_x, ef_z);
    aggB_mfma<<<2048, 256, 0, stream>>>(ts_x, ts_z, h_to_x, h_to_z,
                                        hx_logit, hz_logit,
                                        BW_x, BW_z, W2_x, W2_z, out);
}

// Round 18
// 146.821 us; speedup vs baseline: 2.6365x; 1.0959x over previous
//
#include <hip/hip_runtime.h>

// Problem constants (from reference)
#define NVN 65536
#define NCN 32768
#define NB 4
#define DIM 32
#define NE 262144
#define HID 40
#define MSGD 20
#define SLOT 40        // edge slots per check node (Poisson(8) max-deg ~25 << 40)

typedef unsigned short u16;
typedef unsigned int u32;
typedef __attribute__((ext_vector_type(8))) short bf16x8;
typedef __attribute__((ext_vector_type(4))) float f32x4;

// bf16 helpers (RNE pack, cheap unpack)
__device__ __forceinline__ u16 f2bf(float f) {
    u32 u = __float_as_uint(f);
    u += 0x7fff + ((u >> 16) & 1);
    return (u16)(u >> 16);
}
__device__ __forceinline__ float bflo(u32 u) { return __uint_as_float(u << 16); }
__device__ __forceinline__ float bfhi(u32 u) { return __uint_as_float(u & 0xffff0000u); }
__device__ __forceinline__ u32 pk2(float a, float b) {
    return (u32)f2bf(a) | ((u32)f2bf(b) << 16);
}

// ---------------- direct slot-scatter ----------------

__global__ __launch_bounds__(256) void scatter_slot(const int* __restrict__ to_x,
                                                    const int* __restrict__ from_x,
                                                    const int* __restrict__ to_z,
                                                    const int* __restrict__ from_z,
                                                    int* __restrict__ cnt_x,
                                                    int* __restrict__ cnt_z,
                                                    u16* __restrict__ ef_x,
                                                    u16* __restrict__ ef_z) {
    int bid = blockIdx.x;
    int e = (bid & 1023) * 256 + threadIdx.x;
    const int* t; const int* f; int* cnt; u16* ef;
    if (bid < 1024) { t = to_x; f = from_x; cnt = cnt_x; ef = ef_x; }
    else            { t = to_z; f = from_z; cnt = cnt_z; ef = ef_z; }
    int c = t[e];
    int pos = atomicAdd(&cnt[c], 1);
    if (pos < SLOT) ef[c * SLOT + pos] = (u16)f[e];
}

// ------- precomp_mfma: D[b][row][0:40] = h[b][row][0:32] @ W[32][40], bf16 MFMA -------
// Block = (side, 32 node-rows x ALL 4 batches) -> M=128 rows (m = b*32 + vloc).
// r17 lesson: per-b blocks wrote 2/8 chunks of each 320B line -> partial-cache-line
// writes, WRITE_SIZE 104MB vs 42MB ideal. Now all 8 chunks assembled in LDS and each
// block writes 32 COMPLETE lines (10,240 contiguous bytes, coalesced uint4).

__global__ __launch_bounds__(256) void precomp_mfma(
        const float* __restrict__ h_x, const float* __restrict__ h_z,
        const float* __restrict__ W_x, const float* __restrict__ W_z,
        u16* __restrict__ dst_x, u16* __restrict__ dst_z,
        int nrows) {
    __shared__ __attribute__((aligned(16))) u16 sA[128 * 32];   //  8 KB
    __shared__ __attribute__((aligned(16))) u16 sB[32 * 48];    //  3 KB
    __shared__ __attribute__((aligned(16))) u16 sOut[128 * 40]; // 10 KB

    int bps = nrows >> 5;            // blocks per side
    int bid = blockIdx.x;
    int side = bid / bps;
    int v0 = (bid - side * bps) << 5;

    const float* __restrict__ h = side ? h_z : h_x;
    const float* __restrict__ W = side ? W_z : W_x;
    u16* dst = side ? dst_z : dst_x;

    int tid = threadIdx.x;

    // stage B: [32][48] bf16, cols 40..47 zero
    for (int i = tid; i < 32 * 48; i += 256) {
        int row = i / 48, col = i - row * 48;
        sB[i] = (col < 40) ? f2bf(W[row * 40 + col]) : (u16)0;
    }
    // stage A: 128 rows (m = b*32+vloc) x 32 bf16; thread (r,p) converts 16 floats
    {
        int r = tid >> 1, p = tid & 1;
        int b = r >> 5, vloc = r & 31;
        const float4* hp = (const float4*)(h + ((size_t)b * nrows + v0 + vloc) * DIM + p * 16);
        float4 x0 = hp[0], x1 = hp[1], x2 = hp[2], x3 = hp[3];
        uint4* d = (uint4*)(sA + r * 32 + p * 16);
        d[0] = make_uint4(pk2(x0.x, x0.y), pk2(x0.z, x0.w), pk2(x1.x, x1.y), pk2(x1.z, x1.w));
        d[1] = make_uint4(pk2(x2.x, x2.y), pk2(x2.z, x2.w), pk2(x3.x, x3.y), pk2(x3.z, x3.w));
    }
    __syncthreads();

    int wid = tid >> 6;
    int lane = tid & 63;
    int li = lane & 15;
    int lk = lane >> 4;

    // B frags: 3 col-tiles, single K=32 step
    bf16x8 bfr[3];
#pragma unroll
    for (int jt = 0; jt < 3; jt++) {
        bf16x8 v;
#pragma unroll
        for (int rr = 0; rr < 8; rr++)
            v[rr] = (short)sB[(lk * 8 + rr) * 48 + jt * 16 + li];
        bfr[jt] = v;
    }

#pragma unroll
    for (int rt = 0; rt < 2; rt++) {
        int rowloc = wid * 32 + rt * 16;
        bf16x8 a = *(const bf16x8*)(sA + (rowloc + li) * 32 + lk * 8);
#pragma unroll
        for (int jt = 0; jt < 3; jt++) {
            f32x4 acc = {0.f, 0.f, 0.f, 0.f};
            acc = __builtin_amdgcn_mfma_f32_16x16x32_bf16(a, bfr[jt], acc, 0, 0, 0);
            int col = jt * 16 + li;
            if (col < 40) {
#pragma unroll
                for (int rr = 0; rr < 4; rr++)
                    sOut[(rowloc + lk * 4 + rr) * 40 + col] = f2bf(acc[rr]);
            }
        }
    }
    __syncthreads();

    // write 32 complete 320B lines (10,240B contiguous), uint4-coalesced.
    // dest u32 q within a line: seg0 q<32: ch=q>>2, col=(ch>>2)*20+2*(q&3);
    // seg1 q<64: ch=(q-32)>>2, col=+8; seg2: ch=(q-64)>>1, col=+16.  m=(ch&3)*32+vloc.
    {
        const u32* so = (const u32*)sOut;   // [128][20] packed col-pairs
        uint4* dp = (uint4*)((char*)dst + (size_t)v0 * 320);
        for (int i = tid; i < 640; i += 256) {
            int vloc = i / 20;
            int q0 = (i - vloc * 20) * 4;
            u32 vals[4];
#pragma unroll
            for (int j = 0; j < 4; j++) {
                int q = q0 + j;
                int ch, cp;   // cp = col/2
                if (q < 32)      { ch = q >> 2;        cp = (ch >> 2) * 10 + (q & 3); }
                else if (q < 64) { int t = q - 32; ch = t >> 2; cp = (ch >> 2) * 10 + 4 + (t & 3); }
                else             { int t = q - 64; ch = t >> 1; cp = (ch >> 2) * 10 + 8 + (t & 1); }
                int m = (ch & 3) * 32 + vloc;
                vals[j] = so[m * 20 + cp];
            }
            dp[i] = make_uint4(vals[0], vals[1], vals[2], vals[3]);
        }
    }
}

// ------- prepW: per side, build padded bf16 weight mats for the MFMA GEMMs -------

__global__ __launch_bounds__(256) void prepW(
        const float* __restrict__ Wm2_x, const float* __restrict__ Wm2_z,
        const float* __restrict__ We1_x, const float* __restrict__ We1_z,
        const float* __restrict__ We2_x, const float* __restrict__ We2_z,
        u16* __restrict__ BW_x, u16* __restrict__ BW_z,
        u16* __restrict__ W2_x, u16* __restrict__ W2_z) {
    int side = blockIdx.x;
    const float* Wm2 = side ? Wm2_z : Wm2_x;
    const float* We1 = side ? We1_z : We1_x;
    const float* We2 = side ? We2_z : We2_x;
    u16* BW = side ? BW_z : BW_x;
    u16* W2 = side ? W2_z : W2_x;
    int tid = threadIdx.x;
    for (int i = tid; i < 96 * 48; i += 256) {
        int row = i / 48, col = i % 48;
        float v = 0.f;
        if (col < 40) {
            if (row < 40) {
                for (int k = 0; k < MSGD; k++) v += Wm2[row * MSGD + k] * We1[k * HID + col];
            } else if (row < 72) {
                v = We1[(MSGD + row - 40) * HID + col];
            } else if (row == 72) {
                v = We1[(MSGD + DIM) * HID + col];
            }
        }
        BW[i] = f2bf(v);
    }
    for (int i = tid; i < 64 * 32; i += 256) {
        int row = i / 32, col = i % 32;
        W2[i] = (row < 40) ? f2bf(We2[row * 32 + col]) : (u16)0;
    }
}

// ------- aggA: pure gather+relu-sum, BOTH sides. UNCHANGED (r14/r15, fast). -------

__global__ __launch_bounds__(256, 8) void aggA_kernel(
        const u16* __restrict__ U2h_x, const u16* __restrict__ U2h_z,
        u16* __restrict__ ts_x, u16* __restrict__ ts_z,
        const int* __restrict__ cnt_x, const int* __restrict__ cnt_z,
        const u16* __restrict__ ef_x, const u16* __restrict__ ef_z) {
    int side = blockIdx.x >> 10;
    const char* Ubase = (const char*)(side ? U2h_z : U2h_x);
    char* ts = (char*)(side ? ts_z : ts_x);
    const int* cnt = side ? cnt_z : cnt_x;
    const u16* ef = side ? ef_z : ef_x;

    int gt = (blockIdx.x & 1023) * 256 + threadIdx.x;
    int c = gt >> 3;
    int l8 = gt & 7;
    int off16a = l8 * 16;
    int off8c = 256 + l8 * 8;

    char* tline = ts + (size_t)c * 320;
    uint4 T0 = *(const uint4*)(tline + off16a);
    uint4 T1 = *(const uint4*)(tline + off16a + 128);
    uint2 Tc = *(const uint2*)(tline + off8c);

    float s[20];
#pragma unroll
    for (int k = 0; k < 20; k++) s[k] = 0.f;

    int cn = cnt[c];
    cn = (cn < SLOT) ? cn : SLOT;
    const u16* efc = ef + c * SLOT;

    int vA = (cn > 0) ? (int)efc[0] : 0;
#define ACC(su, aw, tw) { \
    s[su]     += fmaxf(bflo(aw) + bflo(tw), 0.f); \
    s[(su)+1] += fmaxf(bfhi(aw) + bfhi(tw), 0.f); }
    for (int i = 0; i < cn; ++i) {
        const char* pa = Ubase + (size_t)vA * 320;
        uint4 A0 = *(const uint4*)(pa + off16a);
        uint4 A1 = *(const uint4*)(pa + off16a + 128);
        uint2 A2 = *(const uint2*)(pa + off8c);
        vA = (i + 1 < cn) ? (int)efc[i + 1] : 0;
        ACC(0, A0.x, T0.x)  ACC(2, A0.y, T0.y)  ACC(4, A0.z, T0.z)  ACC(6, A0.w, T0.w)
        ACC(8, A1.x, T1.x)  ACC(10, A1.y, T1.y) ACC(12, A1.z, T1.z) ACC(14, A1.w, T1.w)
        ACC(16, A2.x, Tc.x) ACC(18, A2.y, Tc.y)
    }
#undef ACC

    u32 sp[10];
#pragma unroll
    for (int jq = 0; jq < 5; jq++) {
        sp[2 * jq]     = pk2(s[4 * jq + 0], s[4 * jq + 1]);
        sp[2 * jq + 1] = pk2(s[4 * jq + 2], s[4 * jq + 3]);
    }
    *(uint4*)(tline + off16a)       = make_uint4(sp[0], sp[1], sp[2], sp[3]);
    *(uint4*)(tline + off16a + 128) = make_uint4(sp[4], sp[5], sp[6], sp[7]);
    *(uint2*)(tline + off8c)        = make_uint2(sp[8], sp[9]);
}

// ------- aggB_mfma: H = relu([s|X|lg] @ BW) ; out = H @ We2  (UNCHANGED, r16) -------

__global__ __launch_bounds__(256) void aggB_mfma(
        const u16* __restrict__ ts_x, const u16* __restrict__ ts_z,
        const float* __restrict__ h_to_x, const float* __restrict__ h_to_z,
        const float* __restrict__ logit_x, const float* __restrict__ logit_z,
        const u16* __restrict__ BW_x, const u16* __restrict__ BW_z,
        const u16* __restrict__ W2_x, const u16* __restrict__ W2_z,
        float* __restrict__ out) {
    __shared__ __attribute__((aligned(16))) u16 sA[128 * 96];   // 24,576 B
    __shared__ __attribute__((aligned(16))) u16 sH[128 * 64];   // 16,384 B
    __shared__ __attribute__((aligned(16))) u16 sBW[96 * 48];   //  9,216 B
    __shared__ __attribute__((aligned(16))) u16 sW2[64 * 32];   //  4,096 B

    int bid = blockIdx.x;
    int side = bid >> 10;
    const u16* ts = side ? ts_z : ts_x;
    const float* h_to = side ? h_to_z : h_to_x;
    const float* logit = side ? logit_z : logit_x;
    const u16* BWg = side ? BW_z : BW_x;
    const u16* W2g = side ? W2_z : W2_x;

    int tid = threadIdx.x;
    int rho0 = (bid & 1023) * 128;   // within-side row base
    int b = rho0 >> 15;              // uniform over the block
    int c0 = rho0 & 32767;

    for (int i = tid; i < (96 * 48) / 8; i += 256)
        ((uint4*)sBW)[i] = ((const uint4*)BWg)[i];
    if (tid < (64 * 32) / 8) ((uint4*)sW2)[tid] = ((const uint4*)W2g)[tid];

    {
        int r = tid >> 1;
        int part = tid & 1;
        int c = c0 + r;
        char* srow = (char*)sA + r * 192;
        if (part == 0) {
            const char* tr = (const char*)ts + (size_t)c * 320;
            uint4 p0 = *(const uint4*)(tr + b * 16);
            uint4 p1 = *(const uint4*)(tr + 128 + b * 16);
            uint2 p2 = *(const uint2*)(tr + 256 + b * 8);
            uint4 p3 = *(const uint4*)(tr + (4 + b) * 16);
            uint4 p4 = *(const uint4*)(tr + 128 + (4 + b) * 16);
            uint2 p5 = *(const uint2*)(tr + 256 + (4 + b) * 8);
            *(uint4*)(srow + 0)  = p0;
            *(uint4*)(srow + 16) = p1;
            *(uint2*)(srow + 32) = p2;
            *(uint2*)(srow + 40) = make_uint2(p3.x, p3.y);
            *(uint2*)(srow + 48) = make_uint2(p3.z, p3.w);
            *(uint2*)(srow + 56) = make_uint2(p4.x, p4.y);
            *(uint2*)(srow + 64) = make_uint2(p4.z, p4.w);
            *(uint2*)(srow + 72) = p5;
            char* hrow = (char*)sH + r * 128;
            *(uint4*)(hrow + 96)  = make_uint4(0, 0, 0, 0);
            *(uint4*)(hrow + 112) = make_uint4(0, 0, 0, 0);
        } else {
            const float4* xp = (const float4*)(h_to + ((size_t)b * NCN + c) * DIM);
#pragma unroll
            for (int q = 0; q < 4; q++) {
                float4 x0 = xp[2 * q], x1 = xp[2 * q + 1];
                *(uint4*)(srow + 80 + q * 16) =
                    make_uint4(pk2(x0.x, x0.y), pk2(x0.z, x0.w),
                               pk2(x1.x, x1.y), pk2(x1.z, x1.w));
            }
            float lg = logit[(size_t)b * NCN + c];
            *(uint4*)(srow + 144) = make_uint4((u32)f2bf(lg), 0, 0, 0);
            *(uint4*)(srow + 160) = make_uint4(0, 0, 0, 0);
            *(uint4*)(srow + 176) = make_uint4(0, 0, 0, 0);
        }
    }
    __syncthreads();

    int wid = tid >> 6;
    int lane = tid & 63;
    int li = lane & 15;
    int lk = lane >> 4;
    int rowq = lk * 4;

    bf16x8 bA[3][3];
#pragma unroll
    for (int jt = 0; jt < 3; jt++)
#pragma unroll
        for (int ks = 0; ks < 3; ks++) {
            bf16x8 v;
#pragma unroll
            for (int rr = 0; rr < 8; rr++)
                v[rr] = (short)sBW[(ks * 32 + lk * 8 + rr) * 48 + jt * 16 + li];
            bA[jt][ks] = v;
        }

#pragma unroll
    for (int rt = 0; rt < 2; rt++) {
        int rowloc = wid * 32 + rt * 16;
        const char* abase = (const char*)sA + (rowloc + li) * 192 + lk * 16;
        bf16x8 a0 = *(const bf16x8*)(abase);
        bf16x8 a1 = *(const bf16x8*)(abase + 64);
        bf16x8 a2 = *(const bf16x8*)(abase + 128);
#pragma unroll
        for (int jt = 0; jt < 3; jt++) {
            f32x4 acc = {0.f, 0.f, 0.f, 0.f};
            acc = __builtin_amdgcn_mfma_f32_16x16x32_bf16(a0, bA[jt][0], acc, 0, 0, 0);
            acc = __builtin_amdgcn_mfma_f32_16x16x32_bf16(a1, bA[jt][1], acc, 0, 0, 0);
            acc = __builtin_amdgcn_mfma_f32_16x16x32_bf16(a2, bA[jt][2], acc, 0, 0, 0);
#pragma unroll
            for (int rr = 0; rr < 4; rr++)
                sH[(rowloc + rowq + rr) * 64 + jt * 16 + li] = f2bf(fmaxf(acc[rr], 0.f));
        }
    }
    __syncthreads();

    bf16x8 bB[2][2];
#pragma unroll
    for (int jt = 0; jt < 2; jt++)
#pragma unroll
        for (int ks = 0; ks < 2; ks++) {
            bf16x8 v;
#pragma unroll
            for (int rr = 0; rr < 8; rr++)
                v[rr] = (short)sW2[(ks * 32 + lk * 8 + rr) * 32 + jt * 16 + li];
            bB[jt][ks] = v;
        }

    size_t rowg0 = (size_t)bid * 128;
#pragma unroll
    for (int rt = 0; rt < 2; rt++) {
        int rowloc = wid * 32 + rt * 16;
        const char* hbase = (const char*)sH + (rowloc + li) * 128 + lk * 16;
        bf16x8 h0 = *(const bf16x8*)(hbase);
        bf16x8 h1 = *(const bf16x8*)(hbase + 64);
#pragma unroll
        for (int jt = 0; jt < 2; jt++) {
            f32x4 acc = {0.f, 0.f, 0.f, 0.f};
            acc = __builtin_amdgcn_mfma_f32_16x16x32_bf16(h0, bB[jt][0], acc, 0, 0, 0);
            acc = __builtin_amdgcn_mfma_f32_16x16x32_bf16(h1, bB[jt][1], acc, 0, 0, 0);
#pragma unroll
            for (int rr = 0; rr < 4; rr++)
                out[(rowg0 + rowloc + rowq + rr) * 32 + jt * 16 + li] = acc[rr];
        }
    }
}

// ---------------- host ----------------

extern "C" void kernel_launch(void* const* d_in, const int* in_sizes, int n_in,
                              void* d_out, int out_size, void* d_ws, size_t ws_size,
                              hipStream_t stream) {
    const float* h_from   = (const float*)d_in[0];
    const float* h_to_x   = (const float*)d_in[1];
    const float* h_to_z   = (const float*)d_in[2];
    const float* hx_logit = (const float*)d_in[3];
    const float* hz_logit = (const float*)d_in[4];
    const int*   from_x   = (const int*)d_in[5];
    const int*   to_x     = (const int*)d_in[6];
    const int*   from_z   = (const int*)d_in[7];
    const int*   to_z     = (const int*)d_in[8];
    const float* Wm1_x    = (const float*)d_in[9];
    const float* Wm2_x    = (const float*)d_in[10];
    const float* Wm1_z    = (const float*)d_in[11];
    const float* Wm2_z    = (const float*)d_in[12];
    const float* We1_x    = (const float*)d_in[13];
    const float* We2_x    = (const float*)d_in[14];
    const float* We1_z    = (const float*)d_in[15];
    const float* We2_z    = (const float*)d_in[16];

    // Workspace layout (bytes), end = 68,446,208 (<= proven 85,328,128 budget)
    char* ws = (char*)d_ws;
    u16* U2h_x = (u16*)(ws);                       // 65536*320 = 20,971,520
    u16* U2h_z = (u16*)(ws + 20971520);            // 20,971,520
    u16* ts_x  = (u16*)(ws + 41943040);            // 32768*320 = 10,485,760 (T, then s)
    u16* ts_z  = (u16*)(ws + 52428800);            // 10,485,760
    u16* ef_x  = (u16*)(ws + 62914560);            // 32768*40*2 = 2,621,440
    u16* ef_z  = (u16*)(ws + 65536000);            // 2,621,440
    int* cnt_x = (int*)(ws + 68157440);            // 131,072
    int* cnt_z = (int*)(ws + 68288512);            // 131,072
    u16* BW_x  = (u16*)(ws + 68419584);            // 96*48*2 = 9,216
    u16* BW_z  = (u16*)(ws + 68428800);            // 9,216
    u16* W2_x  = (u16*)(ws + 68438016);            // 64*32*2 = 4,096
    u16* W2_z  = (u16*)(ws + 68442112);            // 4,096
    float* out = (float*)d_out;

    hipMemsetAsync(ws + 68157440, 0, 262144, stream);  // zero cnt_x + cnt_z
    scatter_slot<<<2048, 256, 0, stream>>>(to_x, from_x, to_z, from_z,
                                           cnt_x, cnt_z, ef_x, ef_z);
    // U = h_from @ Wm1[0:32]  (both sides read the same h_from)
    precomp_mfma<<<4096, 256, 0, stream>>>(h_from, h_from, Wm1_x, Wm1_z,
                                           U2h_x, U2h_z, NVN);
    // T = h_to @ Wm1[32:64]
    precomp_mfma<<<2048, 256, 0, stream>>>(h_to_x, h_to_z,
                                           Wm1_x + DIM * HID, Wm1_z + DIM * HID,
                                           ts_x, ts_z, NCN);
    prepW<<<2, 256, 0, stream>>>(Wm2_x, Wm2_z, We1_x, We1_z, We2_x, We2_z,
                                 BW_x, BW_z, W2_x, W2_z);
    aggA_kernel<<<2048, 256, 0, stream>>>(U2h_x, U2h_z, ts_x, ts_z,
                                          cnt_x, cnt_z, ef_x, ef_z);
    aggB_mfma<<<2048, 256, 0, stream>>>(ts_x, ts_z, h_to_x, h_to_z,
                                        hx_logit, hz_logit,
                                        BW_x, BW_z, W2_x, W2_z, out);
}

// Round 19
// 131.208 us; speedup vs baseline: 2.9502x; 1.1190x over previous
//
#include <hip/hip_runtime.h>

// Problem constants (from reference)
#define NVN 65536
#define NCN 32768
#define NB 4
#define DIM 32
#define NE 262144
#define HID 40
#define MSGD 20
#define SLOT 40        // edge slots per check node (Poisson(8) max-deg ~25 << 40)

typedef unsigned short u16;
typedef unsigned int u32;
typedef __attribute__((ext_vector_type(8))) short bf16x8;
typedef __attribute__((ext_vector_type(4))) float f32x4;

// bf16 helpers (RNE pack, cheap unpack)
__device__ __forceinline__ u16 f2bf(float f) {
    u32 u = __float_as_uint(f);
    u += 0x7fff + ((u >> 16) & 1);
    return (u16)(u >> 16);
}
__device__ __forceinline__ float bflo(u32 u) { return __uint_as_float(u << 16); }
__device__ __forceinline__ float bfhi(u32 u) { return __uint_as_float(u & 0xffff0000u); }
__device__ __forceinline__ u32 pk2(float a, float b) {
    return (u32)f2bf(a) | ((u32)f2bf(b) << 16);
}

// ------- precomp body: D[b][row][0:40] = h[b][row][0:32] @ W[32][40], bf16 MFMA -------
// Block = (side, 32 node-rows x ALL 4 batches); writes 32 complete 320B lines.

__device__ __forceinline__ void precomp_body(
        int bidl, int tid,
        const float* __restrict__ h_x, const float* __restrict__ h_z,
        const float* __restrict__ W_x, const float* __restrict__ W_z,
        u16* __restrict__ dst_x, u16* __restrict__ dst_z, int nrows,
        u16* sA, u16* sB, u16* sOut) {
    int bps = nrows >> 5;            // blocks per side
    int side = bidl / bps;
    int v0 = (bidl - side * bps) << 5;

    const float* __restrict__ h = side ? h_z : h_x;
    const float* __restrict__ W = side ? W_z : W_x;
    u16* dst = side ? dst_z : dst_x;

    for (int i = tid; i < 32 * 48; i += 256) {
        int row = i / 48, col = i - row * 48;
        sB[i] = (col < 40) ? f2bf(W[row * 40 + col]) : (u16)0;
    }
    {
        int r = tid >> 1, p = tid & 1;
        int b = r >> 5, vloc = r & 31;
        const float4* hp = (const float4*)(h + ((size_t)b * nrows + v0 + vloc) * DIM + p * 16);
        float4 x0 = hp[0], x1 = hp[1], x2 = hp[2], x3 = hp[3];
        uint4* d = (uint4*)(sA + r * 32 + p * 16);
        d[0] = make_uint4(pk2(x0.x, x0.y), pk2(x0.z, x0.w), pk2(x1.x, x1.y), pk2(x1.z, x1.w));
        d[1] = make_uint4(pk2(x2.x, x2.y), pk2(x2.z, x2.w), pk2(x3.x, x3.y), pk2(x3.z, x3.w));
    }
    __syncthreads();

    int wid = tid >> 6;
    int lane = tid & 63;
    int li = lane & 15;
    int lk = lane >> 4;

    bf16x8 bfr[3];
#pragma unroll
    for (int jt = 0; jt < 3; jt++) {
        bf16x8 v;
#pragma unroll
        for (int rr = 0; rr < 8; rr++)
            v[rr] = (short)sB[(lk * 8 + rr) * 48 + jt * 16 + li];
        bfr[jt] = v;
    }

#pragma unroll
    for (int rt = 0; rt < 2; rt++) {
        int rowloc = wid * 32 + rt * 16;
        bf16x8 a = *(const bf16x8*)(sA + (rowloc + li) * 32 + lk * 8);
#pragma unroll
        for (int jt = 0; jt < 3; jt++) {
            f32x4 acc = {0.f, 0.f, 0.f, 0.f};
            acc = __builtin_amdgcn_mfma_f32_16x16x32_bf16(a, bfr[jt], acc, 0, 0, 0);
            int col = jt * 16 + li;
            if (col < 40) {
#pragma unroll
                for (int rr = 0; rr < 4; rr++)
                    sOut[(rowloc + lk * 4 + rr) * 40 + col] = f2bf(acc[rr]);
            }
        }
    }
    __syncthreads();

    {
        const u32* so = (const u32*)sOut;   // [128][20] packed col-pairs
        uint4* dp = (uint4*)((char*)dst + (size_t)v0 * 320);
        for (int i = tid; i < 640; i += 256) {
            int vloc = i / 20;
            int q0 = (i - vloc * 20) * 4;
            u32 vals[4];
#pragma unroll
            for (int j = 0; j < 4; j++) {
                int q = q0 + j;
                int ch, cp;
                if (q < 32)      { ch = q >> 2;        cp = (ch >> 2) * 10 + (q & 3); }
                else if (q < 64) { int t = q - 32; ch = t >> 2; cp = (ch >> 2) * 10 + 4 + (t & 3); }
                else             { int t = q - 64; ch = t >> 1; cp = (ch >> 2) * 10 + 8 + (t & 1); }
                int m = (ch & 3) * 32 + vloc;
                vals[j] = so[m * 20 + cp];
            }
            dp[i] = make_uint4(vals[0], vals[1], vals[2], vals[3]);
        }
    }
}

// ------- phase1: scatter + precompU + precompT + prepW in ONE dispatch -------
// All four are mutually independent; stream order would serialize them as separate
// launches (~3 extra dispatch boundaries). Block routing:
//   [0,2048)      scatter (atomic-bound)        [2048,6144) precompU (MFMA)
//   [6144,8192)   precompT (MFMA)               [8192,8194) prepW

__global__ __launch_bounds__(256) void phase1(
        const int* __restrict__ to_x, const int* __restrict__ from_x,
        const int* __restrict__ to_z, const int* __restrict__ from_z,
        int* __restrict__ cnt_x, int* __restrict__ cnt_z,
        u16* __restrict__ ef_x, u16* __restrict__ ef_z,
        const float* __restrict__ h_from,
        const float* __restrict__ h_to_x, const float* __restrict__ h_to_z,
        const float* __restrict__ Wm1_x, const float* __restrict__ Wm1_z,
        const float* __restrict__ Wm2_x, const float* __restrict__ Wm2_z,
        const float* __restrict__ We1_x, const float* __restrict__ We1_z,
        const float* __restrict__ We2_x, const float* __restrict__ We2_z,
        u16* __restrict__ U2h_x, u16* __restrict__ U2h_z,
        u16* __restrict__ ts_x, u16* __restrict__ ts_z,
        u16* __restrict__ BW_x, u16* __restrict__ BW_z,
        u16* __restrict__ W2_x, u16* __restrict__ W2_z) {
    __shared__ __attribute__((aligned(16))) u16 sA[128 * 32];
    __shared__ __attribute__((aligned(16))) u16 sB[32 * 48];
    __shared__ __attribute__((aligned(16))) u16 sOut[128 * 40];

    int bid = blockIdx.x;
    int tid = threadIdx.x;

    if (bid < 2048) {
        // ---- scatter_slot ----
        int e = (bid & 1023) * 256 + tid;
        const int* t; const int* f; int* cnt; u16* ef;
        if (bid < 1024) { t = to_x; f = from_x; cnt = cnt_x; ef = ef_x; }
        else            { t = to_z; f = from_z; cnt = cnt_z; ef = ef_z; }
        int c = t[e];
        int pos = atomicAdd(&cnt[c], 1);
        if (pos < SLOT) ef[c * SLOT + pos] = (u16)f[e];
    } else if (bid < 6144) {
        // ---- precompU: U = h_from @ Wm1[0:32] ----
        precomp_body(bid - 2048, tid, h_from, h_from, Wm1_x, Wm1_z,
                     U2h_x, U2h_z, NVN, sA, sB, sOut);
    } else if (bid < 8192) {
        // ---- precompT: T = h_to @ Wm1[32:64] ----
        precomp_body(bid - 6144, tid, h_to_x, h_to_z,
                     Wm1_x + DIM * HID, Wm1_z + DIM * HID,
                     ts_x, ts_z, NCN, sA, sB, sOut);
    } else {
        // ---- prepW ----
        int side = bid - 8192;
        const float* Wm2 = side ? Wm2_z : Wm2_x;
        const float* We1 = side ? We1_z : We1_x;
        const float* We2 = side ? We2_z : We2_x;
        u16* BW = side ? BW_z : BW_x;
        u16* W2 = side ? W2_z : W2_x;
        for (int i = tid; i < 96 * 48; i += 256) {
            int row = i / 48, col = i % 48;
            float v = 0.f;
            if (col < 40) {
                if (row < 40) {
                    for (int k = 0; k < MSGD; k++) v += Wm2[row * MSGD + k] * We1[k * HID + col];
                } else if (row < 72) {
                    v = We1[(MSGD + row - 40) * HID + col];
                } else if (row == 72) {
                    v = We1[(MSGD + DIM) * HID + col];
                }
            }
            BW[i] = f2bf(v);
        }
        for (int i = tid; i < 64 * 32; i += 256) {
            int row = i / 32, col = i % 32;
            W2[i] = (row < 40) ? f2bf(We2[row * 32 + col]) : (u16)0;
        }
    }
}

// ------- aggA: pure gather+relu-sum, 16 lanes/node (edge-parity split) -------
// r18: aggA was the top kernel (41us, VALUBusy 31%, occ 54%) — latency-bound on
// ~8 serial dependent gather rounds. Parity split halves rounds; safe here because
// (unlike r6) there is NO matvec to duplicate — post-loop is just pack+store.
// s merged via shfl_xor(8); store guarded to parity 0. VGPR target <= 64.

__global__ __launch_bounds__(256, 8) void aggA_kernel(
        const u16* __restrict__ U2h_x, const u16* __restrict__ U2h_z,
        u16* __restrict__ ts_x, u16* __restrict__ ts_z,
        const int* __restrict__ cnt_x, const int* __restrict__ cnt_z,
        const u16* __restrict__ ef_x, const u16* __restrict__ ef_z) {
    int side = blockIdx.x >> 11;
    const char* Ubase = (const char*)(side ? U2h_z : U2h_x);
    char* ts = (char*)(side ? ts_z : ts_x);
    const int* cnt = side ? cnt_z : cnt_x;
    const u16* ef = side ? ef_z : ef_x;

    int gt = (blockIdx.x & 2047) * 256 + threadIdx.x;
    int c = gt >> 4;
    int l16 = gt & 15;
    int chunk = l16 & 7;
    int par = l16 >> 3;
    int off16a = chunk * 16;
    int off8c = 256 + chunk * 8;

    char* tline = ts + (size_t)c * 320;
    uint4 T0 = *(const uint4*)(tline + off16a);
    uint4 T1 = *(const uint4*)(tline + off16a + 128);
    uint2 Tc = *(const uint2*)(tline + off8c);

    float s[20];
#pragma unroll
    for (int k = 0; k < 20; k++) s[k] = 0.f;

    int cn = cnt[c];
    cn = (cn < SLOT) ? cn : SLOT;
    const u16* efc = ef + c * SLOT;

    int vA = (par < cn) ? (int)efc[par] : 0;
#define ACC(su, aw, tw) { \
    s[su]     += fmaxf(bflo(aw) + bflo(tw), 0.f); \
    s[(su)+1] += fmaxf(bfhi(aw) + bfhi(tw), 0.f); }
    for (int i = par; i < cn; i += 2) {
        const char* pa = Ubase + (size_t)vA * 320;
        uint4 A0 = *(const uint4*)(pa + off16a);
        uint4 A1 = *(const uint4*)(pa + off16a + 128);
        uint2 A2 = *(const uint2*)(pa + off8c);
        vA = (i + 2 < cn) ? (int)efc[i + 2] : 0;
        ACC(0, A0.x, T0.x)  ACC(2, A0.y, T0.y)  ACC(4, A0.z, T0.z)  ACC(6, A0.w, T0.w)
        ACC(8, A1.x, T1.x)  ACC(10, A1.y, T1.y) ACC(12, A1.z, T1.z) ACC(14, A1.w, T1.w)
        ACC(16, A2.x, Tc.x) ACC(18, A2.y, Tc.y)
    }
#undef ACC

    // merge the two parities (lane ^ 8 = other parity, same chunk & c)
#pragma unroll
    for (int k = 0; k < 20; k++) s[k] += __shfl_xor(s[k], 8);

    if (par == 0) {
        u32 sp[10];
#pragma unroll
        for (int jq = 0; jq < 5; jq++) {
            sp[2 * jq]     = pk2(s[4 * jq + 0], s[4 * jq + 1]);
            sp[2 * jq + 1] = pk2(s[4 * jq + 2], s[4 * jq + 3]);
        }
        *(uint4*)(tline + off16a)       = make_uint4(sp[0], sp[1], sp[2], sp[3]);
        *(uint4*)(tline + off16a + 128) = make_uint4(sp[4], sp[5], sp[6], sp[7]);
        *(uint2*)(tline + off8c)        = make_uint2(sp[8], sp[9]);
    }
}

// ------- aggB_mfma: H = relu([s|X|lg] @ BW) ; out = H @ We2  (UNCHANGED, r16) -------

__global__ __launch_bounds__(256) void aggB_mfma(
        const u16* __restrict__ ts_x, const u16* __restrict__ ts_z,
        const float* __restrict__ h_to_x, const float* __restrict__ h_to_z,
        const float* __restrict__ logit_x, const float* __restrict__ logit_z,
        const u16* __restrict__ BW_x, const u16* __restrict__ BW_z,
        const u16* __restrict__ W2_x, const u16* __restrict__ W2_z,
        float* __restrict__ out) {
    __shared__ __attribute__((aligned(16))) u16 sA[128 * 96];   // 24,576 B
    __shared__ __attribute__((aligned(16))) u16 sH[128 * 64];   // 16,384 B
    __shared__ __attribute__((aligned(16))) u16 sBW[96 * 48];   //  9,216 B
    __shared__ __attribute__((aligned(16))) u16 sW2[64 * 32];   //  4,096 B

    int bid = blockIdx.x;
    int side = bid >> 10;
    const u16* ts = side ? ts_z : ts_x;
    const float* h_to = side ? h_to_z : h_to_x;
    const float* logit = side ? logit_z : logit_x;
    const u16* BWg = side ? BW_z : BW_x;
    const u16* W2g = side ? W2_z : W2_x;

    int tid = threadIdx.x;
    int rho0 = (bid & 1023) * 128;   // within-side row base
    int b = rho0 >> 15;              // uniform over the block
    int c0 = rho0 & 32767;

    for (int i = tid; i < (96 * 48) / 8; i += 256)
        ((uint4*)sBW)[i] = ((const uint4*)BWg)[i];
    if (tid < (64 * 32) / 8) ((uint4*)sW2)[tid] = ((const uint4*)W2g)[tid];

    {
        int r = tid >> 1;
        int part = tid & 1;
        int c = c0 + r;
        char* srow = (char*)sA + r * 192;
        if (part == 0) {
            const char* tr = (const char*)ts + (size_t)c * 320;
            uint4 p0 = *(const uint4*)(tr + b * 16);
            uint4 p1 = *(const uint4*)(tr + 128 + b * 16);
            uint2 p2 = *(const uint2*)(tr + 256 + b * 8);
            uint4 p3 = *(const uint4*)(tr + (4 + b) * 16);
            uint4 p4 = *(const uint4*)(tr + 128 + (4 + b) * 16);
            uint2 p5 = *(const uint2*)(tr + 256 + (4 + b) * 8);
            *(uint4*)(srow + 0)  = p0;
            *(uint4*)(srow + 16) = p1;
            *(uint2*)(srow + 32) = p2;
            *(uint2*)(srow + 40) = make_uint2(p3.x, p3.y);
            *(uint2*)(srow + 48) = make_uint2(p3.z, p3.w);
            *(uint2*)(srow + 56) = make_uint2(p4.x, p4.y);
            *(uint2*)(srow + 64) = make_uint2(p4.z, p4.w);
            *(uint2*)(srow + 72) = p5;
            char* hrow = (char*)sH + r * 128;
            *(uint4*)(hrow + 96)  = make_uint4(0, 0, 0, 0);
            *(uint4*)(hrow + 112) = make_uint4(0, 0, 0, 0);
        } else {
            const float4* xp = (const float4*)(h_to + ((size_t)b * NCN + c) * DIM);
#pragma unroll
            for (int q = 0; q < 4; q++) {
                float4 x0 = xp[2 * q], x1 = xp[2 * q + 1];
                *(uint4*)(srow + 80 + q * 16) =
                    make_uint4(pk2(x0.x, x0.y), pk2(x0.z, x0.w),
                               pk2(x1.x, x1.y), pk2(x1.z, x1.w));
            }
            float lg = logit[(size_t)b * NCN + c];
            *(uint4*)(srow + 144) = make_uint4((u32)f2bf(lg), 0, 0, 0);
            *(uint4*)(srow + 160) = make_uint4(0, 0, 0, 0);
            *(uint4*)(srow + 176) = make_uint4(0, 0, 0, 0);
        }
    }
    __syncthreads();

    int wid = tid >> 6;
    int lane = tid & 63;
    int li = lane & 15;
    int lk = lane >> 4;
    int rowq = lk * 4;

    bf16x8 bA[3][3];
#pragma unroll
    for (int jt = 0; jt < 3; jt++)
#pragma unroll
        for (int ks = 0; ks < 3; ks++) {
            bf16x8 v;
#pragma unroll
            for (int rr = 0; rr < 8; rr++)
                v[rr] = (short)sBW[(ks * 32 + lk * 8 + rr) * 48 + jt * 16 + li];
            bA[jt][ks] = v;
        }

#pragma unroll
    for (int rt = 0; rt < 2; rt++) {
        int rowloc = wid * 32 + rt * 16;
        const char* abase = (const char*)sA + (rowloc + li) * 192 + lk * 16;
        bf16x8 a0 = *(const bf16x8*)(abase);
        bf16x8 a1 = *(const bf16x8*)(abase + 64);
        bf16x8 a2 = *(const bf16x8*)(abase + 128);
#pragma unroll
        for (int jt = 0; jt < 3; jt++) {
            f32x4 acc = {0.f, 0.f, 0.f, 0.f};
            acc = __builtin_amdgcn_mfma_f32_16x16x32_bf16(a0, bA[jt][0], acc, 0, 0, 0);
            acc = __builtin_amdgcn_mfma_f32_16x16x32_bf16(a1, bA[jt][1], acc, 0, 0, 0);
            acc = __builtin_amdgcn_mfma_f32_16x16x32_bf16(a2, bA[jt][2], acc, 0, 0, 0);
#pragma unroll
            for (int rr = 0; rr < 4; rr++)
                sH[(rowloc + rowq + rr) * 64 + jt * 16 + li] = f2bf(fmaxf(acc[rr], 0.f));
        }
    }
    __syncthreads();

    bf16x8 bB[2][2];
#pragma unroll
    for (int jt = 0; jt < 2; jt++)
#pragma unroll
        for (int ks = 0; ks < 2; ks++) {
            bf16x8 v;
#pragma unroll
            for (int rr = 0; rr < 8; rr++)
                v[rr] = (short)sW2[(ks * 32 + lk * 8 + rr) * 32 + jt * 16 + li];
            bB[jt][ks] = v;
        }

    size_t rowg0 = (size_t)bid * 128;
#pragma unroll
    for (int rt = 0; rt < 2; rt++) {
        int rowloc = wid * 32 + rt * 16;
        const char* hbase = (const char*)sH + (rowloc + li) * 128 + lk * 16;
        bf16x8 h0 = *(const bf16x8*)(hbase);
        bf16x8 h1 = *(const bf16x8*)(hbase + 64);
#pragma unroll
        for (int jt = 0; jt < 2; jt++) {
            f32x4 acc = {0.f, 0.f, 0.f, 0.f};
            acc = __builtin_amdgcn_mfma_f32_16x16x32_bf16(h0, bB[jt][0], acc, 0, 0, 0);
            acc = __builtin_amdgcn_mfma_f32_16x16x32_bf16(h1, bB[jt][1], acc, 0, 0, 0);
#pragma unroll
            for (int rr = 0; rr < 4; rr++)
                out[(rowg0 + rowloc + rowq + rr) * 32 + jt * 16 + li] = acc[rr];
        }
    }
}

// ---------------- host ----------------

extern "C" void kernel_launch(void* const* d_in, const int* in_sizes, int n_in,
                              void* d_out, int out_size, void* d_ws, size_t ws_size,
                              hipStream_t stream) {
    const float* h_from   = (const float*)d_in[0];
    const float* h_to_x   = (const float*)d_in[1];
    const float* h_to_z   = (const float*)d_in[2];
    const float* hx_logit = (const float*)d_in[3];
    const float* hz_logit = (const float*)d_in[4];
    const int*   from_x   = (const int*)d_in[5];
    const int*   to_x     = (const int*)d_in[6];
    const int*   from_z   = (const int*)d_in[7];
    const int*   to_z     = (const int*)d_in[8];
    const float* Wm1_x    = (const float*)d_in[9];
    const float* Wm2_x    = (const float*)d_in[10];
    const float* Wm1_z    = (const float*)d_in[11];
    const float* Wm2_z    = (const float*)d_in[12];
    const float* We1_x    = (const float*)d_in[13];
    const float* We2_x    = (const float*)d_in[14];
    const float* We1_z    = (const float*)d_in[15];
    const float* We2_z    = (const float*)d_in[16];

    // Workspace layout (bytes), end = 68,446,208 (<= proven 85,328,128 budget)
    char* ws = (char*)d_ws;
    u16* U2h_x = (u16*)(ws);                       // 65536*320 = 20,971,520
    u16* U2h_z = (u16*)(ws + 20971520);            // 20,971,520
    u16* ts_x  = (u16*)(ws + 41943040);            // 32768*320 = 10,485,760 (T, then s)
    u16* ts_z  = (u16*)(ws + 52428800);            // 10,485,760
    u16* ef_x  = (u16*)(ws + 62914560);            // 32768*40*2 = 2,621,440
    u16* ef_z  = (u16*)(ws + 65536000);            // 2,621,440
    int* cnt_x = (int*)(ws + 68157440);            // 131,072
    int* cnt_z = (int*)(ws + 68288512);            // 131,072
    u16* BW_x  = (u16*)(ws + 68419584);            // 96*48*2 = 9,216
    u16* BW_z  = (u16*)(ws + 68428800);            // 9,216
    u16* W2_x  = (u16*)(ws + 68438016);            // 64*32*2 = 4,096
    u16* W2_z  = (u16*)(ws + 68442112);            // 4,096
    float* out = (float*)d_out;

    hipMemsetAsync(ws + 68157440, 0, 262144, stream);  // zero cnt_x + cnt_z
    phase1<<<8194, 256, 0, stream>>>(to_x, from_x, to_z, from_z,
                                     cnt_x, cnt_z, ef_x, ef_z,
                                     h_from, h_to_x, h_to_z,
                                     Wm1_x, Wm1_z, Wm2_x, Wm2_z,
                                     We1_x, We1_z, We2_x, We2_z,
                                     U2h_x, U2h_z, ts_x, ts_z,
                                     BW_x, BW_z, W2_x, W2_z);
    aggA_kernel<<<4096, 256, 0, stream>>>(U2h_x, U2h_z, ts_x, ts_z,
                                          cnt_x, cnt_z, ef_x, ef_z);
    aggB_mfma<<<2048, 256, 0, stream>>>(ts_x, ts_z, h_to_x, h_to_z,
                                        hx_logit, hz_logit,
                                        BW_x, BW_z, W2_x, W2_z, out);
}

// Round 20
// 129.564 us; speedup vs baseline: 2.9876x; 1.0127x over previous
//
#include <hip/hip_runtime.h>

// Problem constants (from reference)
#define NVN 65536
#define NCN 32768
#define NB 4
#define DIM 32
#define NE 262144
#define HID 40
#define MSGD 20
#define SLOT 40        // edge slots per check node (Poisson(8) max-deg ~25 << 40)

typedef unsigned short u16;
typedef unsigned int u32;
typedef __attribute__((ext_vector_type(8))) short bf16x8;
typedef __attribute__((ext_vector_type(4))) float f32x4;

// bf16 helpers (RNE pack, cheap unpack)
__device__ __forceinline__ u16 f2bf(float f) {
    u32 u = __float_as_uint(f);
    u += 0x7fff + ((u >> 16) & 1);
    return (u16)(u >> 16);
}
__device__ __forceinline__ float bflo(u32 u) { return __uint_as_float(u << 16); }
__device__ __forceinline__ float bfhi(u32 u) { return __uint_as_float(u & 0xffff0000u); }
__device__ __forceinline__ u32 pk2(float a, float b) {
    return (u32)f2bf(a) | ((u32)f2bf(b) << 16);
}

// ------- shared repack: sOut[128][40] bf16 -> 32 complete 320B lines at dst+v0*320 -------

__device__ __forceinline__ void repack_lines(int tid, const u16* sOut, u16* dst, int v0) {
    const u32* so = (const u32*)sOut;   // [128][20] packed col-pairs
    uint4* dp = (uint4*)((char*)dst + (size_t)v0 * 320);
    for (int i = tid; i < 640; i += 256) {
        int vloc = i / 20;
        int q0 = (i - vloc * 20) * 4;
        u32 vals[4];
#pragma unroll
        for (int j = 0; j < 4; j++) {
            int q = q0 + j;
            int ch, cp;
            if (q < 32)      { ch = q >> 2;        cp = (ch >> 2) * 10 + (q & 3); }
            else if (q < 64) { int t = q - 32; ch = t >> 2; cp = (ch >> 2) * 10 + 4 + (t & 3); }
            else             { int t = q - 64; ch = t >> 1; cp = (ch >> 2) * 10 + 8 + (t & 1); }
            int m = (ch & 3) * 32 + vloc;
            vals[j] = so[m * 20 + cp];
        }
        dp[i] = make_uint4(vals[0], vals[1], vals[2], vals[3]);
    }
}

// ------- precompU both sides in ONE pass: h_from read/converted ONCE (r19: it was
// read twice, 33.5MB + 8M f2bf wasted). Both sides' B tiles in LDS; MFMA set runs
// twice off the same A fragments; two repacks. -------

__device__ __forceinline__ void precompU_both_body(
        int bidl, int tid, const float* __restrict__ h_from,
        const float* __restrict__ Wx, const float* __restrict__ Wz,
        u16* __restrict__ dstx, u16* __restrict__ dstz,
        u16* sA, u16* sB, u16* sOut) {
    int v0 = bidl << 5;

    for (int i = tid; i < 2 * 1536; i += 256) {
        int sd = (i >= 1536);
        int idx = sd ? i - 1536 : i;
        int row = idx / 48, col = idx - row * 48;
        const float* W = sd ? Wz : Wx;
        sB[i] = (col < 40) ? f2bf(W[row * 40 + col]) : (u16)0;
    }
    {
        int r = tid >> 1, p = tid & 1;
        int b = r >> 5, vloc = r & 31;
        const float4* hp = (const float4*)(h_from + ((size_t)b * NVN + v0 + vloc) * DIM + p * 16);
        float4 x0 = hp[0], x1 = hp[1], x2 = hp[2], x3 = hp[3];
        uint4* d = (uint4*)(sA + r * 32 + p * 16);
        d[0] = make_uint4(pk2(x0.x, x0.y), pk2(x0.z, x0.w), pk2(x1.x, x1.y), pk2(x1.z, x1.w));
        d[1] = make_uint4(pk2(x2.x, x2.y), pk2(x2.z, x2.w), pk2(x3.x, x3.y), pk2(x3.z, x3.w));
    }
    __syncthreads();

    int wid = tid >> 6;
    int lane = tid & 63;
    int li = lane & 15;
    int lk = lane >> 4;

    bf16x8 bfr[2][3];
#pragma unroll
    for (int s = 0; s < 2; s++)
#pragma unroll
        for (int jt = 0; jt < 3; jt++) {
            bf16x8 v;
#pragma unroll
            for (int rr = 0; rr < 8; rr++)
                v[rr] = (short)sB[s * 1536 + (lk * 8 + rr) * 48 + jt * 16 + li];
            bfr[s][jt] = v;
        }
    bf16x8 a0 = *(const bf16x8*)(sA + (wid * 32 + li) * 32 + lk * 8);
    bf16x8 a1 = *(const bf16x8*)(sA + (wid * 32 + 16 + li) * 32 + lk * 8);

#pragma unroll
    for (int s = 0; s < 2; s++) {
        if (s) __syncthreads();   // prior repack's sOut reads complete before overwrite
#pragma unroll
        for (int rt = 0; rt < 2; rt++) {
            int rowloc = wid * 32 + rt * 16;
            bf16x8 a = rt ? a1 : a0;
#pragma unroll
            for (int jt = 0; jt < 3; jt++) {
                f32x4 acc = {0.f, 0.f, 0.f, 0.f};
                acc = __builtin_amdgcn_mfma_f32_16x16x32_bf16(a, bfr[s][jt], acc, 0, 0, 0);
                int col = jt * 16 + li;
                if (col < 40) {
#pragma unroll
                    for (int rr = 0; rr < 4; rr++)
                        sOut[(rowloc + lk * 4 + rr) * 40 + col] = f2bf(acc[rr]);
                }
            }
        }
        __syncthreads();
        repack_lines(tid, sOut, s ? dstz : dstx, v0);
    }
}

// ------- precompT body (single side per block, as r19) -------

__device__ __forceinline__ void precompT_body(
        int bidl, int tid,
        const float* __restrict__ h_x, const float* __restrict__ h_z,
        const float* __restrict__ W_x, const float* __restrict__ W_z,
        u16* __restrict__ dst_x, u16* __restrict__ dst_z,
        u16* sA, u16* sB, u16* sOut) {
    int bps = NCN >> 5;
    int side = bidl / bps;
    int v0 = (bidl - side * bps) << 5;

    const float* __restrict__ h = side ? h_z : h_x;
    const float* __restrict__ W = side ? W_z : W_x;
    u16* dst = side ? dst_z : dst_x;

    for (int i = tid; i < 1536; i += 256) {
        int row = i / 48, col = i - row * 48;
        sB[i] = (col < 40) ? f2bf(W[row * 40 + col]) : (u16)0;
    }
    {
        int r = tid >> 1, p = tid & 1;
        int b = r >> 5, vloc = r & 31;
        const float4* hp = (const float4*)(h + ((size_t)b * NCN + v0 + vloc) * DIM + p * 16);
        float4 x0 = hp[0], x1 = hp[1], x2 = hp[2], x3 = hp[3];
        uint4* d = (uint4*)(sA + r * 32 + p * 16);
        d[0] = make_uint4(pk2(x0.x, x0.y), pk2(x0.z, x0.w), pk2(x1.x, x1.y), pk2(x1.z, x1.w));
        d[1] = make_uint4(pk2(x2.x, x2.y), pk2(x2.z, x2.w), pk2(x3.x, x3.y), pk2(x3.z, x3.w));
    }
    __syncthreads();

    int wid = tid >> 6;
    int lane = tid & 63;
    int li = lane & 15;
    int lk = lane >> 4;

    bf16x8 bfr[3];
#pragma unroll
    for (int jt = 0; jt < 3; jt++) {
        bf16x8 v;
#pragma unroll
        for (int rr = 0; rr < 8; rr++)
            v[rr] = (short)sB[(lk * 8 + rr) * 48 + jt * 16 + li];
        bfr[jt] = v;
    }

#pragma unroll
    for (int rt = 0; rt < 2; rt++) {
        int rowloc = wid * 32 + rt * 16;
        bf16x8 a = *(const bf16x8*)(sA + (rowloc + li) * 32 + lk * 8);
#pragma unroll
        for (int jt = 0; jt < 3; jt++) {
            f32x4 acc = {0.f, 0.f, 0.f, 0.f};
            acc = __builtin_amdgcn_mfma_f32_16x16x32_bf16(a, bfr[jt], acc, 0, 0, 0);
            int col = jt * 16 + li;
            if (col < 40) {
#pragma unroll
                for (int rr = 0; rr < 4; rr++)
                    sOut[(rowloc + lk * 4 + rr) * 40 + col] = f2bf(acc[rr]);
            }
        }
    }
    __syncthreads();
    repack_lines(tid, sOut, dst, v0);
}

// ------- phase1: scatter + precompU(both) + precompT + prepW in ONE dispatch -------
//   [0,2048)  scatter (atomic)   [2048,4096) precompU both sides (MFMA)
//   [4096,6144) precompT (MFMA)  [6144,6146) prepW

__global__ __launch_bounds__(256) void phase1(
        const int* __restrict__ to_x, const int* __restrict__ from_x,
        const int* __restrict__ to_z, const int* __restrict__ from_z,
        int* __restrict__ cnt_x, int* __restrict__ cnt_z,
        u16* __restrict__ ef_x, u16* __restrict__ ef_z,
        const float* __restrict__ h_from,
        const float* __restrict__ h_to_x, const float* __restrict__ h_to_z,
        const float* __restrict__ Wm1_x, const float* __restrict__ Wm1_z,
        const float* __restrict__ Wm2_x, const float* __restrict__ Wm2_z,
        const float* __restrict__ We1_x, const float* __restrict__ We1_z,
        const float* __restrict__ We2_x, const float* __restrict__ We2_z,
        u16* __restrict__ U2h_x, u16* __restrict__ U2h_z,
        u16* __restrict__ ts_x, u16* __restrict__ ts_z,
        u16* __restrict__ BW_x, u16* __restrict__ BW_z,
        u16* __restrict__ W2_x, u16* __restrict__ W2_z) {
    __shared__ __attribute__((aligned(16))) u16 sA[128 * 32];   //  8 KB
    __shared__ __attribute__((aligned(16))) u16 sB[2 * 1536];   //  6 KB
    __shared__ __attribute__((aligned(16))) u16 sOut[128 * 40]; // 10 KB

    int bid = blockIdx.x;
    int tid = threadIdx.x;

    if (bid < 2048) {
        int e = (bid & 1023) * 256 + tid;
        const int* t; const int* f; int* cnt; u16* ef;
        if (bid < 1024) { t = to_x; f = from_x; cnt = cnt_x; ef = ef_x; }
        else            { t = to_z; f = from_z; cnt = cnt_z; ef = ef_z; }
        int c = t[e];
        int pos = atomicAdd(&cnt[c], 1);
        if (pos < SLOT) ef[c * SLOT + pos] = (u16)f[e];
    } else if (bid < 4096) {
        precompU_both_body(bid - 2048, tid, h_from, Wm1_x, Wm1_z,
                           U2h_x, U2h_z, sA, sB, sOut);
    } else if (bid < 6144) {
        precompT_body(bid - 4096, tid, h_to_x, h_to_z,
                      Wm1_x + DIM * HID, Wm1_z + DIM * HID,
                      ts_x, ts_z, sA, sB, sOut);
    } else {
        int side = bid - 6144;
        const float* Wm2 = side ? Wm2_z : Wm2_x;
        const float* We1 = side ? We1_z : We1_x;
        const float* We2 = side ? We2_z : We2_x;
        u16* BW = side ? BW_z : BW_x;
        u16* W2 = side ? W2_z : W2_x;
        for (int i = tid; i < 96 * 48; i += 256) {
            int row = i / 48, col = i % 48;
            float v = 0.f;
            if (col < 40) {
                if (row < 40) {
                    for (int k = 0; k < MSGD; k++) v += Wm2[row * MSGD + k] * We1[k * HID + col];
                } else if (row < 72) {
                    v = We1[(MSGD + row - 40) * HID + col];
                } else if (row == 72) {
                    v = We1[(MSGD + DIM) * HID + col];
                }
            }
            BW[i] = f2bf(v);
        }
        for (int i = tid; i < 64 * 32; i += 256) {
            int row = i / 32, col = i % 32;
            W2[i] = (row < 40) ? f2bf(We2[row * 32 + col]) : (u16)0;
        }
    }
}

// ------- aggA: pure gather+relu-sum, 16 lanes/node (edge-parity split; r19 WIN) -------

__global__ __launch_bounds__(256, 8) void aggA_kernel(
        const u16* __restrict__ U2h_x, const u16* __restrict__ U2h_z,
        u16* __restrict__ ts_x, u16* __restrict__ ts_z,
        const int* __restrict__ cnt_x, const int* __restrict__ cnt_z,
        const u16* __restrict__ ef_x, const u16* __restrict__ ef_z) {
    int side = blockIdx.x >> 11;
    const char* Ubase = (const char*)(side ? U2h_z : U2h_x);
    char* ts = (char*)(side ? ts_z : ts_x);
    const int* cnt = side ? cnt_z : cnt_x;
    const u16* ef = side ? ef_z : ef_x;

    int gt = (blockIdx.x & 2047) * 256 + threadIdx.x;
    int c = gt >> 4;
    int l16 = gt & 15;
    int chunk = l16 & 7;
    int par = l16 >> 3;
    int off16a = chunk * 16;
    int off8c = 256 + chunk * 8;

    char* tline = ts + (size_t)c * 320;
    uint4 T0 = *(const uint4*)(tline + off16a);
    uint4 T1 = *(const uint4*)(tline + off16a + 128);
    uint2 Tc = *(const uint2*)(tline + off8c);

    float s[20];
#pragma unroll
    for (int k = 0; k < 20; k++) s[k] = 0.f;

    int cn = cnt[c];
    cn = (cn < SLOT) ? cn : SLOT;
    const u16* efc = ef + c * SLOT;

    int vA = (par < cn) ? (int)efc[par] : 0;
#define ACC(su, aw, tw) { \
    s[su]     += fmaxf(bflo(aw) + bflo(tw), 0.f); \
    s[(su)+1] += fmaxf(bfhi(aw) + bfhi(tw), 0.f); }
    for (int i = par; i < cn; i += 2) {
        const char* pa = Ubase + (size_t)vA * 320;
        uint4 A0 = *(const uint4*)(pa + off16a);
        uint4 A1 = *(const uint4*)(pa + off16a + 128);
        uint2 A2 = *(const uint2*)(pa + off8c);
        vA = (i + 2 < cn) ? (int)efc[i + 2] : 0;
        ACC(0, A0.x, T0.x)  ACC(2, A0.y, T0.y)  ACC(4, A0.z, T0.z)  ACC(6, A0.w, T0.w)
        ACC(8, A1.x, T1.x)  ACC(10, A1.y, T1.y) ACC(12, A1.z, T1.z) ACC(14, A1.w, T1.w)
        ACC(16, A2.x, Tc.x) ACC(18, A2.y, Tc.y)
    }
#undef ACC

#pragma unroll
    for (int k = 0; k < 20; k++) s[k] += __shfl_xor(s[k], 8);

    if (par == 0) {
        u32 sp[10];
#pragma unroll
        for (int jq = 0; jq < 5; jq++) {
            sp[2 * jq]     = pk2(s[4 * jq + 0], s[4 * jq + 1]);
            sp[2 * jq + 1] = pk2(s[4 * jq + 2], s[4 * jq + 3]);
        }
        *(uint4*)(tline + off16a)       = make_uint4(sp[0], sp[1], sp[2], sp[3]);
        *(uint4*)(tline + off16a + 128) = make_uint4(sp[4], sp[5], sp[6], sp[7]);
        *(uint2*)(tline + off8c)        = make_uint2(sp[8], sp[9]);
    }
}

// ------- aggB_mfma: H = relu([s|X|lg] @ BW) ; out = H @ We2  (UNCHANGED, r16) -------

__global__ __launch_bounds__(256) void aggB_mfma(
        const u16* __restrict__ ts_x, const u16* __restrict__ ts_z,
        const float* __restrict__ h_to_x, const float* __restrict__ h_to_z,
        const float* __restrict__ logit_x, const float* __restrict__ logit_z,
        const u16* __restrict__ BW_x, const u16* __restrict__ BW_z,
        const u16* __restrict__ W2_x, const u16* __restrict__ W2_z,
        float* __restrict__ out) {
    __shared__ __attribute__((aligned(16))) u16 sA[128 * 96];   // 24,576 B
    __shared__ __attribute__((aligned(16))) u16 sH[128 * 64];   // 16,384 B
    __shared__ __attribute__((aligned(16))) u16 sBW[96 * 48];   //  9,216 B
    __shared__ __attribute__((aligned(16))) u16 sW2[64 * 32];   //  4,096 B

    int bid = blockIdx.x;
    int side = bid >> 10;
    const u16* ts = side ? ts_z : ts_x;
    const float* h_to = side ? h_to_z : h_to_x;
    const float* logit = side ? logit_z : logit_x;
    const u16* BWg = side ? BW_z : BW_x;
    const u16* W2g = side ? W2_z : W2_x;

    int tid = threadIdx.x;
    int rho0 = (bid & 1023) * 128;   // within-side row base
    int b = rho0 >> 15;              // uniform over the block
    int c0 = rho0 & 32767;

    for (int i = tid; i < (96 * 48) / 8; i += 256)
        ((uint4*)sBW)[i] = ((const uint4*)BWg)[i];
    if (tid < (64 * 32) / 8) ((uint4*)sW2)[tid] = ((const uint4*)W2g)[tid];

    {
        int r = tid >> 1;
        int part = tid & 1;
        int c = c0 + r;
        char* srow = (char*)sA + r * 192;
        if (part == 0) {
            const char* tr = (const char*)ts + (size_t)c * 320;
            uint4 p0 = *(const uint4*)(tr + b * 16);
            uint4 p1 = *(const uint4*)(tr + 128 + b * 16);
            uint2 p2 = *(const uint2*)(tr + 256 + b * 8);
            uint4 p3 = *(const uint4*)(tr + (4 + b) * 16);
            uint4 p4 = *(const uint4*)(tr + 128 + (4 + b) * 16);
            uint2 p5 = *(const uint2*)(tr + 256 + (4 + b) * 8);
            *(uint4*)(srow + 0)  = p0;
            *(uint4*)(srow + 16) = p1;
            *(uint2*)(srow + 32) = p2;
            *(uint2*)(srow + 40) = make_uint2(p3.x, p3.y);
            *(uint2*)(srow + 48) = make_uint2(p3.z, p3.w);
            *(uint2*)(srow + 56) = make_uint2(p4.x, p4.y);
            *(uint2*)(srow + 64) = make_uint2(p4.z, p4.w);
            *(uint2*)(srow + 72) = p5;
            char* hrow = (char*)sH + r * 128;
            *(uint4*)(hrow + 96)  = make_uint4(0, 0, 0, 0);
            *(uint4*)(hrow + 112) = make_uint4(0, 0, 0, 0);
        } else {
            const float4* xp = (const float4*)(h_to + ((size_t)b * NCN + c) * DIM);
#pragma unroll
            for (int q = 0; q < 4; q++) {
                float4 x0 = xp[2 * q], x1 = xp[2 * q + 1];
                *(uint4*)(srow + 80 + q * 16) =
                    make_uint4(pk2(x0.x, x0.y), pk2(x0.z, x0.w),
                               pk2(x1.x, x1.y), pk2(x1.z, x1.w));
            }
            float lg = logit[(size_t)b * NCN + c];
            *(uint4*)(srow + 144) = make_uint4((u32)f2bf(lg), 0, 0, 0);
            *(uint4*)(srow + 160) = make_uint4(0, 0, 0, 0);
            *(uint4*)(srow + 176) = make_uint4(0, 0, 0, 0);
        }
    }
    __syncthreads();

    int wid = tid >> 6;
    int lane = tid & 63;
    int li = lane & 15;
    int lk = lane >> 4;
    int rowq = lk * 4;

    bf16x8 bA[3][3];
#pragma unroll
    for (int jt = 0; jt < 3; jt++)
#pragma unroll
        for (int ks = 0; ks < 3; ks++) {
            bf16x8 v;
#pragma unroll
            for (int rr = 0; rr < 8; rr++)
                v[rr] = (short)sBW[(ks * 32 + lk * 8 + rr) * 48 + jt * 16 + li];
            bA[jt][ks] = v;
        }

#pragma unroll
    for (int rt = 0; rt < 2; rt++) {
        int rowloc = wid * 32 + rt * 16;
        const char* abase = (const char*)sA + (rowloc + li) * 192 + lk * 16;
        bf16x8 a0 = *(const bf16x8*)(abase);
        bf16x8 a1 = *(const bf16x8*)(abase + 64);
        bf16x8 a2 = *(const bf16x8*)(abase + 128);
#pragma unroll
        for (int jt = 0; jt < 3; jt++) {
            f32x4 acc = {0.f, 0.f, 0.f, 0.f};
            acc = __builtin_amdgcn_mfma_f32_16x16x32_bf16(a0, bA[jt][0], acc, 0, 0, 0);
            acc = __builtin_amdgcn_mfma_f32_16x16x32_bf16(a1, bA[jt][1], acc, 0, 0, 0);
            acc = __builtin_amdgcn_mfma_f32_16x16x32_bf16(a2, bA[jt][2], acc, 0, 0, 0);
#pragma unroll
            for (int rr = 0; rr < 4; rr++)
                sH[(rowloc + rowq + rr) * 64 + jt * 16 + li] = f2bf(fmaxf(acc[rr], 0.f));
        }
    }
    __syncthreads();

    bf16x8 bB[2][2];
#pragma unroll
    for (int jt = 0; jt < 2; jt++)
#pragma unroll
        for (int ks = 0; ks < 2; ks++) {
            bf16x8 v;
#pragma unroll
            for (int rr = 0; rr < 8; rr++)
                v[rr] = (short)sW2[(ks * 32 + lk * 8 + rr) * 32 + jt * 16 + li];
            bB[jt][ks] = v;
        }

    size_t rowg0 = (size_t)bid * 128;
#pragma unroll
    for (int rt = 0; rt < 2; rt++) {
        int rowloc = wid * 32 + rt * 16;
        const char* hbase = (const char*)sH + (rowloc + li) * 128 + lk * 16;
        bf16x8 h0 = *(const bf16x8*)(hbase);
        bf16x8 h1 = *(const bf16x8*)(hbase + 64);
#pragma unroll
        for (int jt = 0; jt < 2; jt++) {
            f32x4 acc = {0.f, 0.f, 0.f, 0.f};
            acc = __builtin_amdgcn_mfma_f32_16x16x32_bf16(h0, bB[jt][0], acc, 0, 0, 0);
            acc = __builtin_amdgcn_mfma_f32_16x16x32_bf16(h1, bB[jt][1], acc, 0, 0, 0);
#pragma unroll
            for (int rr = 0; rr < 4; rr++)
                out[(rowg0 + rowloc + rowq + rr) * 32 + jt * 16 + li] = acc[rr];
        }
    }
}

// ---------------- host ----------------

extern "C" void kernel_launch(void* const* d_in, const int* in_sizes, int n_in,
                              void* d_out, int out_size, void* d_ws, size_t ws_size,
                              hipStream_t stream) {
    const float* h_from   = (const float*)d_in[0];
    const float* h_to_x   = (const float*)d_in[1];
    const float* h_to_z   = (const float*)d_in[2];
    const float* hx_logit = (const float*)d_in[3];
    const float* hz_logit = (const float*)d_in[4];
    const int*   from_x   = (const int*)d_in[5];
    const int*   to_x     = (const int*)d_in[6];
    const int*   from_z   = (const int*)d_in[7];
    const int*   to_z     = (const int*)d_in[8];
    const float* Wm1_x    = (const float*)d_in[9];
    const float* Wm2_x    = (const float*)d_in[10];
    const float* Wm1_z    = (const float*)d_in[11];
    const float* Wm2_z    = (const float*)d_in[12];
    const float* We1_x    = (const float*)d_in[13];
    const float* We2_x    = (const float*)d_in[14];
    const float* We1_z    = (const float*)d_in[15];
    const float* We2_z    = (const float*)d_in[16];

    // Workspace layout (bytes), end = 68,446,208 (<= proven 85,328,128 budget)
    char* ws = (char*)d_ws;
    u16* U2h_x = (u16*)(ws);                       // 65536*320 = 20,971,520
    u16* U2h_z = (u16*)(ws + 20971520);            // 20,971,520
    u16* ts_x  = (u16*)(ws + 41943040);            // 32768*320 = 10,485,760 (T, then s)
    u16* ts_z  = (u16*)(ws + 52428800);            // 10,485,760
    u16* ef_x  = (u16*)(ws + 62914560);            // 32768*40*2 = 2,621,440
    u16* ef_z  = (u16*)(ws + 65536000);            // 2,621,440
    int* cnt_x = (int*)(ws + 68157440);            // 131,072
    int* cnt_z = (int*)(ws + 68288512);            // 131,072
    u16* BW_x  = (u16*)(ws + 68419584);            // 96*48*2 = 9,216
    u16* BW_z  = (u16*)(ws + 68428800);            // 9,216
    u16* W2_x  = (u16*)(ws + 68438016);            // 64*32*2 = 4,096
    u16* W2_z  = (u16*)(ws + 68442112);            // 4,096
    float* out = (float*)d_out;

    hipMemsetAsync(ws + 68157440, 0, 262144, stream);  // zero cnt_x + cnt_z
    phase1<<<6146, 256, 0, stream>>>(to_x, from_x, to_z, from_z,
                                     cnt_x, cnt_z, ef_x, ef_z,
                                     h_from, h_to_x, h_to_z,
                                     Wm1_x, Wm1_z, Wm2_x, Wm2_z,
                                     We1_x, We1_z, We2_x, We2_z,
                                     U2h_x, U2h_z, ts_x, ts_z,
                                     BW_x, BW_z, W2_x, W2_z);
    aggA_kernel<<<4096, 256, 0, stream>>>(U2h_x, U2h_z, ts_x, ts_z,
                                          cnt_x, cnt_z, ef_x, ef_z);
    aggB_mfma<<<2048, 256, 0, stream>>>(ts_x, ts_z, h_to_x, h_to_z,
                                        hx_logit, hz_logit,
                                        BW_x, BW_z, W2_x, W2_z, out);
}